// Round 16
// baseline (217.535 us; speedup 1.0000x reference)
//
#include <hip/hip_runtime.h>
#include <cmath>

#define B_   16
#define C_   256
#define HW_  64
#define N_   4096          // 64*64
#define NH_  8
#define HD_  32
#define M_   (B_ * N_)     // 65536
#define QKVC (3 * C_)      // 768
#define EPS_ 1e-6f

typedef short bf16x8 __attribute__((ext_vector_type(8)));
typedef float f32x4 __attribute__((ext_vector_type(4)));
typedef unsigned int u32x4 __attribute__((ext_vector_type(4)));

__device__ __forceinline__ float b2f(unsigned short u) {
  union { unsigned int i; float f; } v;
  v.i = ((unsigned int)u) << 16;
  return v.f;
}
// bf16 pair extraction from a packed uint (pure register ops)
__device__ __forceinline__ float blo(unsigned int u) {
  union { unsigned int i; float f; } v; v.i = u << 16; return v.f;
}
__device__ __forceinline__ float bhi(unsigned int u) {
  union { unsigned int i; float f; } v; v.i = u & 0xffff0000u; return v.f;
}
__device__ __forceinline__ unsigned short f2b(float f) {
  union { float f; unsigned int i; } v;
  v.f = f;
  unsigned int r = v.i + 0x7FFFu + ((v.i >> 16) & 1u);  // RNE
  return (unsigned short)(r >> 16);
}
__device__ __forceinline__ void gload_lds16(const void* g, void* l) {
  __builtin_amdgcn_global_load_lds(
      (const __attribute__((address_space(1))) void*)g,
      (__attribute__((address_space(3))) void*)l, 16, 0, 0);
}

// ---------------------------------------------------------------------------
// K0a: transpose-cast x [b][c][n] f32 -> xT [b][n][c] bf16
// ---------------------------------------------------------------------------
__global__ __launch_bounds__(256) void k_cast_x(const float* __restrict__ x,
                                                unsigned short* __restrict__ xT) {
  __shared__ float t[32][33];
  const int n0 = blockIdx.x * 32, c0 = blockIdx.y * 32, b = blockIdx.z;
  const int tid = threadIdx.x;
  const int r = tid >> 3, g = (tid & 7) * 4;
  float4 v = *reinterpret_cast<const float4*>(
      &x[((size_t)(b * C_ + c0 + r)) * N_ + n0 + g]);
  t[r][g + 0] = v.x; t[r][g + 1] = v.y; t[r][g + 2] = v.z; t[r][g + 3] = v.w;
  __syncthreads();
  ushort4 o;
  o.x = f2b(t[g + 0][r]); o.y = f2b(t[g + 1][r]);
  o.z = f2b(t[g + 2][r]); o.w = f2b(t[g + 3][r]);
  *reinterpret_cast<ushort4*>(&xT[((size_t)(b * N_ + n0 + r)) * C_ + c0 + g]) = o;
}

// ---------------------------------------------------------------------------
// K0b: cast qkv_w (768x256) and proj_w (256x256) to bf16 (contiguous dst)
// ---------------------------------------------------------------------------
__global__ __launch_bounds__(256) void k_cast_w(const float* __restrict__ w1,
                                                const float* __restrict__ w2,
                                                unsigned short* __restrict__ dst) {
  const int g4 = (blockIdx.x * 256 + threadIdx.x) * 4;  // < 262144
  float4 v;
  if (g4 < 196608) v = *reinterpret_cast<const float4*>(w1 + g4);
  else             v = *reinterpret_cast<const float4*>(w2 + (g4 - 196608));
  ushort4 o;
  o.x = f2b(v.x); o.y = f2b(v.y); o.z = f2b(v.z); o.w = f2b(v.w);
  *reinterpret_cast<ushort4*>(dst + g4) = o;
}

// ---------------------------------------------------------------------------
// K0c: rsc[c] = 1/softplus(scale[c]) — computed ONCE.
// ---------------------------------------------------------------------------
__global__ void k_prep_scale(const float* __restrict__ scale,
                             float* __restrict__ rsc) {
  const int c = threadIdx.x;
  rsc[c] = 1.f / log1pf(expf(scale[c]));
}

// ---------------------------------------------------------------------------
// K1/K6: bf16 MFMA GEMM, 128x128 tile, BK=64, 4 waves (2x2 of 64x64).
// Row-major in-band XCD ordering (round 14: FETCH-bound fix). OUTMODE 0 =
// cached stores (qkv is re-read downstream); OUTMODE 1 = nt (d_out is not).
// ---------------------------------------------------------------------------
template <int LDA, int OUTMODE, int NCOL>
__global__ __launch_bounds__(256) void k_gemm(
    const unsigned short* __restrict__ A, const unsigned short* __restrict__ W,
    const float* __restrict__ bias, void* __restrict__ outp) {
  __shared__ unsigned short As[128 * 64];
  __shared__ unsigned short Bs[128 * 64];
  const int tid = threadIdx.x;
  const int wid = tid >> 6, lane = tid & 63;
  const int lin = blockIdx.x + blockIdx.y * 512;
  const int bandp = lin >> 3;
  const int rowb = bandp / NCOL;
  const int colb = bandp - rowb * NCOL;
  const int m0 = (((lin & 7) << 6) + rowb) * 128;
  const int col0 = colb * 128;
  const int wr = wid >> 1, wc = wid & 1;

  const int lrow = lane >> 3;
  const int sl = (lane & 7) ^ (lrow & 7);  // logical 16B-slot this lane fetches

  f32x4 acc[4][4];
#pragma unroll
  for (int i = 0; i < 4; ++i)
#pragma unroll
    for (int j = 0; j < 4; ++j) acc[i][j] = (f32x4){0.f, 0.f, 0.f, 0.f};

  for (int kt = 0; kt < 4; ++kt) {
    const int k0 = kt * 64;
#pragma unroll
    for (int q = 0; q < 4; ++q) {
      const int chunk = wid * 4 + q;          // 0..15, 8 rows each
      const int row = chunk * 8 + lrow;       // 0..127
      gload_lds16(A + (size_t)(m0 + row) * LDA + k0 + sl * 8, &As[chunk * 512]);
      gload_lds16(W + (size_t)(col0 + row) * 256 + k0 + sl * 8, &Bs[chunk * 512]);
    }
    __syncthreads();  // drains vmcnt -> staged tiles visible

    bf16x8 fa[2][4], fb[2][4];
#pragma unroll
    for (int i = 0; i < 4; ++i) {
      const int ra = wr * 64 + i * 16 + (lane & 15);
      const int rb = wc * 64 + i * 16 + (lane & 15);
#pragma unroll
      for (int ks = 0; ks < 2; ++ks) {
        const int s = ks * 4 + (lane >> 4);
        fa[ks][i] = *reinterpret_cast<const bf16x8*>(
            &As[ra * 64 + ((s ^ (ra & 7)) * 8)]);
        fb[ks][i] = *reinterpret_cast<const bf16x8*>(
            &Bs[rb * 64 + ((s ^ (rb & 7)) * 8)]);
      }
    }
#pragma unroll
    for (int i = 0; i < 4; ++i)
#pragma unroll
      for (int j = 0; j < 4; ++j) {
        acc[i][j] = __builtin_amdgcn_mfma_f32_16x16x32_bf16(fa[0][i], fb[0][j],
                                                            acc[i][j], 0, 0, 0);
        acc[i][j] = __builtin_amdgcn_mfma_f32_16x16x32_bf16(fa[1][i], fb[1][j],
                                                            acc[i][j], 0, 0, 0);
      }
    __syncthreads();
  }

  // C/D layout: col = lane&15, row = (lane>>4)*4 + reg   [m89/m91]
  if (OUTMODE == 0) {
    unsigned short* O = (unsigned short*)outp;
#pragma unroll
    for (int j = 0; j < 4; ++j) {
      const int colg = col0 + wc * 64 + j * 16 + (lane & 15);
      const float bb = bias[colg];
#pragma unroll
      for (int i = 0; i < 4; ++i) {
        const int mrow = m0 + wr * 64 + i * 16 + ((lane >> 4) << 2);
#pragma unroll
        for (int r = 0; r < 4; ++r)
          O[(size_t)(mrow + r) * QKVC + colg] = f2b(acc[i][j][r] + bb);
      }
    }
  } else {
    float* O = (float*)outp;
    const int b = m0 >> 12;
    const int nb0 = (m0 & 4095) + wr * 64;
#pragma unroll
    for (int j = 0; j < 4; ++j) {
      const int colg = col0 + wc * 64 + j * 16 + (lane & 15);
      const float bb = bias[colg];
#pragma unroll
      for (int i = 0; i < 4; ++i) {
        const int nb = nb0 + i * 16 + ((lane >> 4) << 2);
        f32x4 o = acc[i][j];
        o += bb;
        __builtin_nontemporal_store(
            o, reinterpret_cast<f32x4*>(&O[((size_t)(b * C_ + colg)) * N_ + nb]));
      }
    }
  }
}

// ---------------------------------------------------------------------------
// K2: focusing feature map, wave-per-token (round 9).
// ---------------------------------------------------------------------------
__global__ __launch_bounds__(256) void k_focus(unsigned short* __restrict__ qkv,
                                               const float* __restrict__ rsc) {
  const int wave = threadIdx.x >> 6, lane = threadIdx.x & 63;
  const int t = blockIdx.x * 4 + wave;        // token
  const size_t base = (size_t)t * QKVC + lane * 4;

  uint2 qu = *reinterpret_cast<const uint2*>(qkv + base);
  uint2 ku = *reinterpret_cast<const uint2*>(qkv + base + C_);
  const f32x4 rs = *reinterpret_cast<const f32x4*>(rsc + lane * 4);

  float q[4], k[4], q3[4], k3[4];
  q[0] = blo(qu.x); q[1] = bhi(qu.x); q[2] = blo(qu.y); q[3] = bhi(qu.y);
  k[0] = blo(ku.x); k[1] = bhi(ku.x); k[2] = blo(ku.y); k[3] = bhi(ku.y);

  float sq2 = 0.f, sq6 = 0.f, sk2 = 0.f, sk6 = 0.f;
#pragma unroll
  for (int i = 0; i < 4; ++i) {
    q[i] = (fmaxf(q[i], 0.f) + EPS_) * rs[i];
    k[i] = (fmaxf(k[i], 0.f) + EPS_) * rs[i];
    const float q2 = q[i] * q[i], k2 = k[i] * k[i];
    q3[i] = q2 * q[i];
    k3[i] = k2 * k[i];
    sq2 += q2; sk2 += k2;
    sq6 += q3[i] * q3[i];
    sk6 += k3[i] * k3[i];
  }
#pragma unroll
  for (int off = 1; off < 64; off <<= 1) {
    sq2 += __shfl_xor(sq2, off);
    sq6 += __shfl_xor(sq6, off);
    sk2 += __shfl_xor(sk2, off);
    sk6 += __shfl_xor(sk6, off);
  }
  const float fq = sqrtf(sq2 / sq6);
  const float fk = sqrtf(sk2 / sk6);

  uint2 oq, ok;
  oq.x = (unsigned int)f2b(q3[0] * fq) | ((unsigned int)f2b(q3[1] * fq) << 16);
  oq.y = (unsigned int)f2b(q3[2] * fq) | ((unsigned int)f2b(q3[3] * fq) << 16);
  ok.x = (unsigned int)f2b(k3[0] * fk) | ((unsigned int)f2b(k3[1] * fk) << 16);
  ok.y = (unsigned int)f2b(k3[2] * fk) | ((unsigned int)f2b(k3[3] * fk) << 16);
  *reinterpret_cast<uint2*>(qkv + base) = oq;
  *reinterpret_cast<uint2*>(qkv + base + C_) = ok;
}

// ---------------------------------------------------------------------------
// K3: kv partials per (bh, chunk of 512 rows): kvp[c][d], ksump[c]
// ROUND-16: round-15 counters showed FETCH == logical (65 MB) but dur 42 us
// with VALUBusy 22%, occ 30% — barrier-bound: 64 barriers/block around tiny
// 16-row tiles with 8 B staging loads. Restructure: 64-row tiles staged via
// global_load_lds width-16 (1 load k + 1 load v per thread per tile),
// double-buffered with issue-next -> compute-cur -> barrier (9 barriers
// total, loads in flight under compute). ksum piggybacks on the kc loads
// already in registers (8 threads/c accumulate identically; one stores).
// ---------------------------------------------------------------------------
__global__ __launch_bounds__(256) void k_kv_part(
    const unsigned short* __restrict__ qkv, float* __restrict__ kvp,
    float* __restrict__ ksp) {
  const int bh = blockIdx.x;
  const int chunk = blockIdx.y;
  const int b = bh >> 3, h = bh & 7;
  const int tid = threadIdx.x;
  const int wave = tid >> 6;
  __shared__ unsigned short ks[2][64 * 32];  // 4 KB per buf
  __shared__ unsigned short vs[2][64 * 32];

  const int c = tid >> 3;            // 0..31
  const int d0 = (tid & 7) * 4;      // 0,4,..,28
  const int row = tid >> 2;          // staging row 0..63
  const int seg = (tid & 3) * 8;     // staging element offset (16 B)
  const int j0 = chunk * 512;

  float a0 = 0.f, a1 = 0.f, a2 = 0.f, a3 = 0.f, ksum_acc = 0.f;

  // stage 64-row k & v tiles into buf (LDS dest linear: lane*16 per wave)
#define KV_STAGE(buf, jt)                                                     \
  {                                                                           \
    const size_t rb =                                                         \
        ((size_t)(b * N_ + (jt) + row)) * QKVC + h * HD_ + seg;               \
    gload_lds16(qkv + rb + C_, &ks[buf][wave * 512]);                         \
    gload_lds16(qkv + rb + 2 * C_, &vs[buf][wave * 512]);                     \
  }

  KV_STAGE(0, j0);
  __syncthreads();

  int cur = 0;
  for (int t = 0; t < 8; ++t) {
    if (t < 7) KV_STAGE(cur ^ 1, j0 + (t + 1) * 64);  // loads fly under compute
#pragma unroll 8
    for (int jj = 0; jj < 64; ++jj) {
      const float kc = b2f(ks[cur][jj * 32 + c]);
      const uint2 vv =
          *reinterpret_cast<const uint2*>(&vs[cur][jj * 32 + d0]);
      a0 += kc * blo(vv.x);
      a1 += kc * bhi(vv.x);
      a2 += kc * blo(vv.y);
      a3 += kc * bhi(vv.y);
      ksum_acc += kc;  // identical across the 8 threads sharing c
    }
    __syncthreads();  // drains next-tile loads; cur buffer free to overwrite
    cur ^= 1;
  }
#undef KV_STAGE

  float* kvo = kvp + ((size_t)chunk * 128 + bh) * 1024 + c * 32 + d0;
  kvo[0] = a0; kvo[1] = a1; kvo[2] = a2; kvo[3] = a3;
  if ((tid & 7) == 0) ksp[((size_t)chunk * 128 + bh) * 32 + c] = ksum_acc;
}

// ---------------------------------------------------------------------------
// K4a: attention output via MFMA; kv/ksum 8-chunk reduce fused into the
// LDS-load loop (kvp is L2/L3-resident).
// ---------------------------------------------------------------------------
__global__ __launch_bounds__(256) void k_attn_mfma(
    unsigned short* __restrict__ qkv, const float* __restrict__ kvp,
    const float* __restrict__ ksp) {
  const int bh = blockIdx.y;
  const int b = bh >> 3, h = bh & 7;
  const int tid = threadIdx.x;
  const int lane = tid & 63;
  const int r0 = blockIdx.x * 256 + (tid >> 6) * 64;  // wave's first row

  __shared__ float kv_s[1024];
  __shared__ float ksum_s[32];
  for (int pp = tid; pp < 1024; pp += 256) {
    float s = 0.f;
#pragma unroll
    for (int ch = 0; ch < 8; ++ch)
      s += kvp[((size_t)ch * 128 + bh) * 1024 + pp];
    kv_s[pp] = s;
  }
  if (tid < 32) {
    float s = 0.f;
#pragma unroll
    for (int ch = 0; ch < 8; ++ch)
      s += ksp[((size_t)ch * 128 + bh) * 32 + tid];
    ksum_s[tid] = s;
  }
  __syncthreads();

  // B-frag layout (16x16x32): col = lane&15, k = (lane>>4)*8 + t
  const int kb = (lane >> 4) * 8;
  const int col = lane & 15;
  bf16x8 bhi0, bhi1, blo0, blo1;
  float ks0[8];
#pragma unroll
  for (int t = 0; t < 8; ++t) {
    const float v0 = kv_s[(kb + t) * 32 + col];
    const float v1 = kv_s[(kb + t) * 32 + col + 16];
    const unsigned short h0 = f2b(v0), h1 = f2b(v1);
    ((unsigned short*)&bhi0)[t] = h0;
    ((unsigned short*)&bhi1)[t] = h1;
    ((unsigned short*)&blo0)[t] = f2b(v0 - b2f(h0));
    ((unsigned short*)&blo1)[t] = f2b(v1 - b2f(h1));
    ks0[t] = ksum_s[kb + t];
  }

#pragma unroll
  for (int rt = 0; rt < 4; ++rt) {
    const int row = r0 + rt * 16 + (lane & 15);
    const bf16x8 a = *reinterpret_cast<const bf16x8*>(
        qkv + (size_t)(b * N_ + row) * QKVC + h * HD_ + kb);
    float zp = 0.f;
#pragma unroll
    for (int t = 0; t < 8; ++t) zp += b2f(((const unsigned short*)&a)[t]) * ks0[t];
    zp += __shfl_xor(zp, 16);
    zp += __shfl_xor(zp, 32);
    const float z = 1.f / (zp + EPS_);

    f32x4 acc0 = {0.f, 0.f, 0.f, 0.f}, acc1 = {0.f, 0.f, 0.f, 0.f};
    acc0 = __builtin_amdgcn_mfma_f32_16x16x32_bf16(a, blo0, acc0, 0, 0, 0);
    acc1 = __builtin_amdgcn_mfma_f32_16x16x32_bf16(a, blo1, acc1, 0, 0, 0);
    acc0 = __builtin_amdgcn_mfma_f32_16x16x32_bf16(a, bhi0, acc0, 0, 0, 0);
    acc1 = __builtin_amdgcn_mfma_f32_16x16x32_bf16(a, bhi1, acc1, 0, 0, 0);

#pragma unroll
    for (int r = 0; r < 4; ++r) {
      const int rr = (lane >> 4) * 4 + r;
      const float zr = __shfl(z, rr);
      unsigned short* op =
          qkv + (size_t)(b * N_ + r0 + rt * 16 + rr) * QKVC + h * HD_;
      op[col] = f2b(acc0[r] * zr);
      op[col + 16] = f2b(acc1[r] * zr);
    }
  }
}

// ---------------------------------------------------------------------------
// K4b: depthwise 5x5 conv on v, RMW-adds into the q-slot (attn out).
// R=4 rows/block with 8-row halo in LDS; XCD-chunked mapping (round 15).
// ---------------------------------------------------------------------------
__global__ __launch_bounds__(256) void k_conv(
    unsigned short* __restrict__ qkv, const float* __restrict__ dwc_w,
    const float* __restrict__ dwc_b) {
  const int lin = blockIdx.x;               // 0..2047
  const int g2 = (lin & 7) * 256 + (lin >> 3);
  const int bh = g2 >> 4;                   // 0..127
  const int ig = g2 & 15;                   // 4-row group
  const int i0 = ig * 4;
  const int b = bh >> 3, h = bh & 7;
  const int tid = threadIdx.x;
  const int j = tid >> 2;                   // image col (0..63)
  const int g = tid & 3;                    // channel group
  const int d0 = g * 8;
  const int wave = tid >> 6, lane = tid & 63;

  __shared__ float w_s[800];                // [tap][ch]
  __shared__ float b_s[32];
  __shared__ unsigned short v_s[8 * 64 * 32];  // [halo-row][col][ch] 32 KB

  // stage v rows i0-2 .. i0+5 (8 rows; OOB rows skipped, masked at use)
#pragma unroll
  for (int rr = 0; rr < 8; ++rr) {
    const int ii = i0 + rr - 2;             // block-uniform condition
    if (ii < 0 || ii >= 64) continue;
    gload_lds16(qkv + ((size_t)(b * N_ + ii * 64 + wave * 16 + (lane >> 2))) * QKVC +
                    2 * C_ + h * HD_ + (lane & 3) * 8,
                &v_s[rr * 2048 + wave * 512]);
  }
  for (int p = tid; p < 800; p += 256)
    w_s[p] = dwc_w[(p & 31) * 25 + (p >> 5)];
  if (tid < 32) b_s[tid] = dwc_b[tid];
  __syncthreads();   // drains vmcnt -> staged v visible

#pragma unroll
  for (int r = 0; r < 4; ++r) {
    const int i = i0 + r;
    float fm[8];
#pragma unroll
    for (int dd = 0; dd < 8; ++dd) fm[dd] = b_s[d0 + dd];
#pragma unroll
    for (int kr = 0; kr < 5; ++kr) {
      const int ii = i + kr - 2;
      if (ii < 0 || ii >= 64) continue;
      const int lr = r + kr;                // LDS halo row
#pragma unroll
      for (int kj = 0; kj < 5; ++kj) {
        const int jj = j + kj - 2;
        if (jj < 0 || jj >= 64) continue;
        const unsigned int* vr = reinterpret_cast<const unsigned int*>(
            &v_s[lr * 2048 + jj * 32 + d0]);
        const float* wt = &w_s[(kr * 5 + kj) * 32 + d0];
#pragma unroll
        for (int p = 0; p < 4; ++p) {
          const unsigned int vu = vr[p];
          fm[2 * p + 0] += blo(vu) * wt[2 * p + 0];
          fm[2 * p + 1] += bhi(vu) * wt[2 * p + 1];
        }
      }
    }
    // RMW: add conv into attn output (q-slot)
    unsigned int* orow = reinterpret_cast<unsigned int*>(
        qkv + ((size_t)(b * N_ + i * 64 + j)) * QKVC + h * HD_ + d0);
    uint4 cur = *reinterpret_cast<const uint4*>(orow);
    unsigned int o[4] = {cur.x, cur.y, cur.z, cur.w};
#pragma unroll
    for (int p = 0; p < 4; ++p) {
      const unsigned int lo = f2b(blo(o[p]) + fm[2 * p + 0]);
      const unsigned int hi = f2b(bhi(o[p]) + fm[2 * p + 1]);
      o[p] = lo | (hi << 16);
    }
    *reinterpret_cast<uint4*>(orow) = make_uint4(o[0], o[1], o[2], o[3]);
  }
}

// ---------------------------------------------------------------------------
extern "C" void kernel_launch(void* const* d_in, const int* in_sizes, int n_in,
                              void* d_out, int out_size, void* d_ws,
                              size_t ws_size, hipStream_t stream) {
  (void)in_sizes; (void)n_in; (void)out_size; (void)ws_size;
  const float* x      = (const float*)d_in[0];
  const float* qkv_w  = (const float*)d_in[1];
  const float* qkv_b  = (const float*)d_in[2];
  const float* proj_w = (const float*)d_in[3];
  const float* proj_b = (const float*)d_in[4];
  const float* dwc_w  = (const float*)d_in[5];
  const float* dwc_b  = (const float*)d_in[6];
  const float* scale  = (const float*)d_in[7];
  float* out = (float*)d_out;

  char* w = (char*)d_ws;
  unsigned short* xT   = (unsigned short*)w; w += (size_t)M_ * C_ * 2;     // 33.6MB
  unsigned short* qkvb = (unsigned short*)w; w += (size_t)M_ * QKVC * 2;   // 100.7MB
  // Reserve space for BOTH weight matrices (round-3 NaN was wp aliasing kvp).
  unsigned short* wq   = (unsigned short*)w; w += (size_t)(QKVC + C_) * C_ * 2;
  unsigned short* wp   = wq + (size_t)QKVC * C_;
  float* kvp   = (float*)w;                  w += (size_t)8 * 128 * 1024 * 4;
  float* ksp   = (float*)w;                  w += (size_t)8 * 128 * 32 * 4;
  float* rscb  = (float*)w;                  w += 256 * 4;

  k_prep_scale<<<1, 256, 0, stream>>>(scale, rscb);
  k_cast_x<<<dim3(N_ / 32, C_ / 32, B_), 256, 0, stream>>>(x, xT);
  k_cast_w<<<256, 256, 0, stream>>>(qkv_w, proj_w, wq);
  k_gemm<256, 0, 6><<<dim3(512, 6), 256, 0, stream>>>(
      xT, wq, qkv_b, (void*)qkvb);
  k_focus<<<M_ / 4, 256, 0, stream>>>(qkvb, rscb);
  k_kv_part<<<dim3(128, 8), 256, 0, stream>>>(qkvb, kvp, ksp);
  k_attn_mfma<<<dim3(N_ / 256, 128), 256, 0, stream>>>(qkvb, kvp, ksp);
  k_conv<<<2048, 256, 0, stream>>>(qkvb, dwc_w, dwc_b);
  k_gemm<768, 1, 2><<<dim3(512, 2), 256, 0, stream>>>(
      qkvb, wp, proj_b, (void*)out);
}

// Round 17
// 210.720 us; speedup vs baseline: 1.0323x; 1.0323x over previous
//
#include <hip/hip_runtime.h>
#include <cmath>

#define B_   16
#define C_   256
#define HW_  64
#define N_   4096          // 64*64
#define NH_  8
#define HD_  32
#define M_   (B_ * N_)     // 65536
#define QKVC (3 * C_)      // 768
#define EPS_ 1e-6f

typedef short bf16x8 __attribute__((ext_vector_type(8)));
typedef float f32x4 __attribute__((ext_vector_type(4)));
typedef unsigned int u32x4 __attribute__((ext_vector_type(4)));

__device__ __forceinline__ float b2f(unsigned short u) {
  union { unsigned int i; float f; } v;
  v.i = ((unsigned int)u) << 16;
  return v.f;
}
// bf16 pair extraction from a packed uint (pure register ops)
__device__ __forceinline__ float blo(unsigned int u) {
  union { unsigned int i; float f; } v; v.i = u << 16; return v.f;
}
__device__ __forceinline__ float bhi(unsigned int u) {
  union { unsigned int i; float f; } v; v.i = u & 0xffff0000u; return v.f;
}
__device__ __forceinline__ unsigned short f2b(float f) {
  union { float f; unsigned int i; } v;
  v.f = f;
  unsigned int r = v.i + 0x7FFFu + ((v.i >> 16) & 1u);  // RNE
  return (unsigned short)(r >> 16);
}
__device__ __forceinline__ void gload_lds16(const void* g, void* l) {
  __builtin_amdgcn_global_load_lds(
      (const __attribute__((address_space(1))) void*)g,
      (__attribute__((address_space(3))) void*)l, 16, 0, 0);
}

// ---------------------------------------------------------------------------
// K0a: transpose-cast x [b][c][n] f32 -> xT [b][n][c] bf16
// ---------------------------------------------------------------------------
__global__ __launch_bounds__(256) void k_cast_x(const float* __restrict__ x,
                                                unsigned short* __restrict__ xT) {
  __shared__ float t[32][33];
  const int n0 = blockIdx.x * 32, c0 = blockIdx.y * 32, b = blockIdx.z;
  const int tid = threadIdx.x;
  const int r = tid >> 3, g = (tid & 7) * 4;
  float4 v = *reinterpret_cast<const float4*>(
      &x[((size_t)(b * C_ + c0 + r)) * N_ + n0 + g]);
  t[r][g + 0] = v.x; t[r][g + 1] = v.y; t[r][g + 2] = v.z; t[r][g + 3] = v.w;
  __syncthreads();
  ushort4 o;
  o.x = f2b(t[g + 0][r]); o.y = f2b(t[g + 1][r]);
  o.z = f2b(t[g + 2][r]); o.w = f2b(t[g + 3][r]);
  *reinterpret_cast<ushort4*>(&xT[((size_t)(b * N_ + n0 + r)) * C_ + c0 + g]) = o;
}

// ---------------------------------------------------------------------------
// K0b: cast qkv_w (768x256) and proj_w (256x256) to bf16 (contiguous dst)
// ---------------------------------------------------------------------------
__global__ __launch_bounds__(256) void k_cast_w(const float* __restrict__ w1,
                                                const float* __restrict__ w2,
                                                unsigned short* __restrict__ dst) {
  const int g4 = (blockIdx.x * 256 + threadIdx.x) * 4;  // < 262144
  float4 v;
  if (g4 < 196608) v = *reinterpret_cast<const float4*>(w1 + g4);
  else             v = *reinterpret_cast<const float4*>(w2 + (g4 - 196608));
  ushort4 o;
  o.x = f2b(v.x); o.y = f2b(v.y); o.z = f2b(v.z); o.w = f2b(v.w);
  *reinterpret_cast<ushort4*>(dst + g4) = o;
}

// ---------------------------------------------------------------------------
// K0c: rsc[c] = 1/softplus(scale[c]) — computed ONCE.
// ---------------------------------------------------------------------------
__global__ void k_prep_scale(const float* __restrict__ scale,
                             float* __restrict__ rsc) {
  const int c = threadIdx.x;
  rsc[c] = 1.f / log1pf(expf(scale[c]));
}

// ---------------------------------------------------------------------------
// K1/K6: bf16 MFMA GEMM, 128x128 tile, BK=64, 4 waves (2x2 of 64x64).
// Row-major in-band XCD ordering (round 14: FETCH-bound fix). OUTMODE 0 =
// cached stores (qkv is re-read downstream); OUTMODE 1 = nt (d_out is not).
// ---------------------------------------------------------------------------
template <int LDA, int OUTMODE, int NCOL>
__global__ __launch_bounds__(256) void k_gemm(
    const unsigned short* __restrict__ A, const unsigned short* __restrict__ W,
    const float* __restrict__ bias, void* __restrict__ outp) {
  __shared__ unsigned short As[128 * 64];
  __shared__ unsigned short Bs[128 * 64];
  const int tid = threadIdx.x;
  const int wid = tid >> 6, lane = tid & 63;
  const int lin = blockIdx.x + blockIdx.y * 512;
  const int bandp = lin >> 3;
  const int rowb = bandp / NCOL;
  const int colb = bandp - rowb * NCOL;
  const int m0 = (((lin & 7) << 6) + rowb) * 128;
  const int col0 = colb * 128;
  const int wr = wid >> 1, wc = wid & 1;

  const int lrow = lane >> 3;
  const int sl = (lane & 7) ^ (lrow & 7);  // logical 16B-slot this lane fetches

  f32x4 acc[4][4];
#pragma unroll
  for (int i = 0; i < 4; ++i)
#pragma unroll
    for (int j = 0; j < 4; ++j) acc[i][j] = (f32x4){0.f, 0.f, 0.f, 0.f};

  for (int kt = 0; kt < 4; ++kt) {
    const int k0 = kt * 64;
#pragma unroll
    for (int q = 0; q < 4; ++q) {
      const int chunk = wid * 4 + q;          // 0..15, 8 rows each
      const int row = chunk * 8 + lrow;       // 0..127
      gload_lds16(A + (size_t)(m0 + row) * LDA + k0 + sl * 8, &As[chunk * 512]);
      gload_lds16(W + (size_t)(col0 + row) * 256 + k0 + sl * 8, &Bs[chunk * 512]);
    }
    __syncthreads();  // drains vmcnt -> staged tiles visible

    bf16x8 fa[2][4], fb[2][4];
#pragma unroll
    for (int i = 0; i < 4; ++i) {
      const int ra = wr * 64 + i * 16 + (lane & 15);
      const int rb = wc * 64 + i * 16 + (lane & 15);
#pragma unroll
      for (int ks = 0; ks < 2; ++ks) {
        const int s = ks * 4 + (lane >> 4);
        fa[ks][i] = *reinterpret_cast<const bf16x8*>(
            &As[ra * 64 + ((s ^ (ra & 7)) * 8)]);
        fb[ks][i] = *reinterpret_cast<const bf16x8*>(
            &Bs[rb * 64 + ((s ^ (rb & 7)) * 8)]);
      }
    }
#pragma unroll
    for (int i = 0; i < 4; ++i)
#pragma unroll
      for (int j = 0; j < 4; ++j) {
        acc[i][j] = __builtin_amdgcn_mfma_f32_16x16x32_bf16(fa[0][i], fb[0][j],
                                                            acc[i][j], 0, 0, 0);
        acc[i][j] = __builtin_amdgcn_mfma_f32_16x16x32_bf16(fa[1][i], fb[1][j],
                                                            acc[i][j], 0, 0, 0);
      }
    __syncthreads();
  }

  // C/D layout: col = lane&15, row = (lane>>4)*4 + reg   [m89/m91]
  if (OUTMODE == 0) {
    unsigned short* O = (unsigned short*)outp;
#pragma unroll
    for (int j = 0; j < 4; ++j) {
      const int colg = col0 + wc * 64 + j * 16 + (lane & 15);
      const float bb = bias[colg];
#pragma unroll
      for (int i = 0; i < 4; ++i) {
        const int mrow = m0 + wr * 64 + i * 16 + ((lane >> 4) << 2);
#pragma unroll
        for (int r = 0; r < 4; ++r)
          O[(size_t)(mrow + r) * QKVC + colg] = f2b(acc[i][j][r] + bb);
      }
    }
  } else {
    float* O = (float*)outp;
    const int b = m0 >> 12;
    const int nb0 = (m0 & 4095) + wr * 64;
#pragma unroll
    for (int j = 0; j < 4; ++j) {
      const int colg = col0 + wc * 64 + j * 16 + (lane & 15);
      const float bb = bias[colg];
#pragma unroll
      for (int i = 0; i < 4; ++i) {
        const int nb = nb0 + i * 16 + ((lane >> 4) << 2);
        f32x4 o = acc[i][j];
        o += bb;
        __builtin_nontemporal_store(
            o, reinterpret_cast<f32x4*>(&O[((size_t)(b * C_ + colg)) * N_ + nb]));
      }
    }
  }
}

// ---------------------------------------------------------------------------
// K2: focusing feature map, wave-per-token (round 9).
// ---------------------------------------------------------------------------
__global__ __launch_bounds__(256) void k_focus(unsigned short* __restrict__ qkv,
                                               const float* __restrict__ rsc) {
  const int wave = threadIdx.x >> 6, lane = threadIdx.x & 63;
  const int t = blockIdx.x * 4 + wave;        // token
  const size_t base = (size_t)t * QKVC + lane * 4;

  uint2 qu = *reinterpret_cast<const uint2*>(qkv + base);
  uint2 ku = *reinterpret_cast<const uint2*>(qkv + base + C_);
  const f32x4 rs = *reinterpret_cast<const f32x4*>(rsc + lane * 4);

  float q[4], k[4], q3[4], k3[4];
  q[0] = blo(qu.x); q[1] = bhi(qu.x); q[2] = blo(qu.y); q[3] = bhi(qu.y);
  k[0] = blo(ku.x); k[1] = bhi(ku.x); k[2] = blo(ku.y); k[3] = bhi(ku.y);

  float sq2 = 0.f, sq6 = 0.f, sk2 = 0.f, sk6 = 0.f;
#pragma unroll
  for (int i = 0; i < 4; ++i) {
    q[i] = (fmaxf(q[i], 0.f) + EPS_) * rs[i];
    k[i] = (fmaxf(k[i], 0.f) + EPS_) * rs[i];
    const float q2 = q[i] * q[i], k2 = k[i] * k[i];
    q3[i] = q2 * q[i];
    k3[i] = k2 * k[i];
    sq2 += q2; sk2 += k2;
    sq6 += q3[i] * q3[i];
    sk6 += k3[i] * k3[i];
  }
#pragma unroll
  for (int off = 1; off < 64; off <<= 1) {
    sq2 += __shfl_xor(sq2, off);
    sq6 += __shfl_xor(sq6, off);
    sk2 += __shfl_xor(sk2, off);
    sk6 += __shfl_xor(sk6, off);
  }
  const float fq = sqrtf(sq2 / sq6);
  const float fk = sqrtf(sk2 / sk6);

  uint2 oq, ok;
  oq.x = (unsigned int)f2b(q3[0] * fq) | ((unsigned int)f2b(q3[1] * fq) << 16);
  oq.y = (unsigned int)f2b(q3[2] * fq) | ((unsigned int)f2b(q3[3] * fq) << 16);
  ok.x = (unsigned int)f2b(k3[0] * fk) | ((unsigned int)f2b(k3[1] * fk) << 16);
  ok.y = (unsigned int)f2b(k3[2] * fk) | ((unsigned int)f2b(k3[3] * fk) << 16);
  *reinterpret_cast<uint2*>(qkv + base) = oq;
  *reinterpret_cast<uint2*>(qkv + base + C_) = ok;
}

// ---------------------------------------------------------------------------
// K3: kv partials per (bh, chunk of 256 rows): kvp[c][d], ksump[c]
// ROUND-17 (post-mortem r15/r16): r15 = f32-LDS staging but 64 barriers
// (42.5 us); r16 = few barriers but bf16 unpack in inner loop (46.6 us,
// VALU-heavy). Combine: T14 reg-staging (global uint4 -> regs -> convert
// once -> ds_write_b128 into pad-36 f32 LDS), 64-row tiles, next-tile loads
// issued BEFORE compute (latency hides under 64 FMA iters), 8 barriers.
// Pad 36 floats: staging b128 writes hit 32 banks (was 16-way on stride 32);
// reads stay aligned (144 B row pitch) and conflict-free. 16 chunks ->
// 2048 blocks = 8/CU.
// ---------------------------------------------------------------------------
#define KVP_CHUNKS 16
__global__ __launch_bounds__(256) void k_kv_part(
    const unsigned short* __restrict__ qkv, float* __restrict__ kvp,
    float* __restrict__ ksp) {
  const int bh = blockIdx.x;
  const int chunk = blockIdx.y;
  const int b = bh >> 3, h = bh & 7;
  const int tid = threadIdx.x;
  __shared__ float ksf[64 * 36];   // 9.2 KB, row pitch 36 floats (144 B)
  __shared__ float vsf[64 * 36];

  const int c = tid >> 3;            // 0..31
  const int d0 = (tid & 7) * 4;      // 0,4,..,28
  const int srow = tid >> 2;         // staging row 0..63
  const int sseg = (tid & 3) * 8;    // staging element offset
  const int j0 = chunk * 256;

  float a0 = 0.f, a1 = 0.f, a2 = 0.f, a3 = 0.f, ksum = 0.f;

  uint4 ku, vu;
  {
    const size_t rb = ((size_t)(b * N_ + j0 + srow)) * QKVC + h * HD_ + sseg;
    ku = *reinterpret_cast<const uint4*>(qkv + rb + C_);
    vu = *reinterpret_cast<const uint4*>(qkv + rb + 2 * C_);
  }

  for (int t = 0; t < 4; ++t) {
    {  // convert current regs -> f32 LDS (conversion happens ONCE here)
      f32x4 k0 = {blo(ku.x), bhi(ku.x), blo(ku.y), bhi(ku.y)};
      f32x4 k1 = {blo(ku.z), bhi(ku.z), blo(ku.w), bhi(ku.w)};
      f32x4 v0 = {blo(vu.x), bhi(vu.x), blo(vu.y), bhi(vu.y)};
      f32x4 v1 = {blo(vu.z), bhi(vu.z), blo(vu.w), bhi(vu.w)};
      *reinterpret_cast<f32x4*>(&ksf[srow * 36 + sseg]) = k0;
      *reinterpret_cast<f32x4*>(&ksf[srow * 36 + sseg + 4]) = k1;
      *reinterpret_cast<f32x4*>(&vsf[srow * 36 + sseg]) = v0;
      *reinterpret_cast<f32x4*>(&vsf[srow * 36 + sseg + 4]) = v1;
    }
    __syncthreads();
    if (t < 3) {  // issue next-tile loads; they fly under the compute below
      const size_t rb =
          ((size_t)(b * N_ + j0 + (t + 1) * 64 + srow)) * QKVC + h * HD_ + sseg;
      ku = *reinterpret_cast<const uint4*>(qkv + rb + C_);
      vu = *reinterpret_cast<const uint4*>(qkv + rb + 2 * C_);
    }
#pragma unroll 8
    for (int jj = 0; jj < 64; ++jj) {
      const float kc = ksf[jj * 36 + c];
      const f32x4 vv = *reinterpret_cast<const f32x4*>(&vsf[jj * 36 + d0]);
      a0 += kc * vv[0];
      a1 += kc * vv[1];
      a2 += kc * vv[2];
      a3 += kc * vv[3];
      ksum += kc;  // identical across the 8 threads sharing c; one stores
    }
    __syncthreads();  // LDS free to overwrite next iteration
  }

  float* kvo = kvp + ((size_t)chunk * 128 + bh) * 1024 + c * 32 + d0;
  kvo[0] = a0; kvo[1] = a1; kvo[2] = a2; kvo[3] = a3;
  if ((tid & 7) == 0) ksp[((size_t)chunk * 128 + bh) * 32 + c] = ksum;
}

// ---------------------------------------------------------------------------
// K4a: attention output via MFMA; kv/ksum 16-chunk reduce fused into the
// LDS-load loop (kvp = 8 MB, L3-resident).
// ---------------------------------------------------------------------------
__global__ __launch_bounds__(256) void k_attn_mfma(
    unsigned short* __restrict__ qkv, const float* __restrict__ kvp,
    const float* __restrict__ ksp) {
  const int bh = blockIdx.y;
  const int b = bh >> 3, h = bh & 7;
  const int tid = threadIdx.x;
  const int lane = tid & 63;
  const int r0 = blockIdx.x * 256 + (tid >> 6) * 64;  // wave's first row

  __shared__ float kv_s[1024];
  __shared__ float ksum_s[32];
  for (int pp = tid; pp < 1024; pp += 256) {
    float s = 0.f;
#pragma unroll
    for (int ch = 0; ch < KVP_CHUNKS; ++ch)
      s += kvp[((size_t)ch * 128 + bh) * 1024 + pp];
    kv_s[pp] = s;
  }
  if (tid < 32) {
    float s = 0.f;
#pragma unroll
    for (int ch = 0; ch < KVP_CHUNKS; ++ch)
      s += ksp[((size_t)ch * 128 + bh) * 32 + tid];
    ksum_s[tid] = s;
  }
  __syncthreads();

  // B-frag layout (16x16x32): col = lane&15, k = (lane>>4)*8 + t
  const int kb = (lane >> 4) * 8;
  const int col = lane & 15;
  bf16x8 bhi0, bhi1, blo0, blo1;
  float ks0[8];
#pragma unroll
  for (int t = 0; t < 8; ++t) {
    const float v0 = kv_s[(kb + t) * 32 + col];
    const float v1 = kv_s[(kb + t) * 32 + col + 16];
    const unsigned short h0 = f2b(v0), h1 = f2b(v1);
    ((unsigned short*)&bhi0)[t] = h0;
    ((unsigned short*)&bhi1)[t] = h1;
    ((unsigned short*)&blo0)[t] = f2b(v0 - b2f(h0));
    ((unsigned short*)&blo1)[t] = f2b(v1 - b2f(h1));
    ks0[t] = ksum_s[kb + t];
  }

#pragma unroll
  for (int rt = 0; rt < 4; ++rt) {
    const int row = r0 + rt * 16 + (lane & 15);
    const bf16x8 a = *reinterpret_cast<const bf16x8*>(
        qkv + (size_t)(b * N_ + row) * QKVC + h * HD_ + kb);
    float zp = 0.f;
#pragma unroll
    for (int t = 0; t < 8; ++t) zp += b2f(((const unsigned short*)&a)[t]) * ks0[t];
    zp += __shfl_xor(zp, 16);
    zp += __shfl_xor(zp, 32);
    const float z = 1.f / (zp + EPS_);

    f32x4 acc0 = {0.f, 0.f, 0.f, 0.f}, acc1 = {0.f, 0.f, 0.f, 0.f};
    acc0 = __builtin_amdgcn_mfma_f32_16x16x32_bf16(a, blo0, acc0, 0, 0, 0);
    acc1 = __builtin_amdgcn_mfma_f32_16x16x32_bf16(a, blo1, acc1, 0, 0, 0);
    acc0 = __builtin_amdgcn_mfma_f32_16x16x32_bf16(a, bhi0, acc0, 0, 0, 0);
    acc1 = __builtin_amdgcn_mfma_f32_16x16x32_bf16(a, bhi1, acc1, 0, 0, 0);

#pragma unroll
    for (int r = 0; r < 4; ++r) {
      const int rr = (lane >> 4) * 4 + r;
      const float zr = __shfl(z, rr);
      unsigned short* op =
          qkv + (size_t)(b * N_ + r0 + rt * 16 + rr) * QKVC + h * HD_;
      op[col] = f2b(acc0[r] * zr);
      op[col + 16] = f2b(acc1[r] * zr);
    }
  }
}

// ---------------------------------------------------------------------------
// K4b: depthwise 5x5 conv on v, RMW-adds into the q-slot (attn out).
// R=4 rows/block with 8-row halo in LDS; XCD-chunked mapping (round 15).
// ---------------------------------------------------------------------------
__global__ __launch_bounds__(256) void k_conv(
    unsigned short* __restrict__ qkv, const float* __restrict__ dwc_w,
    const float* __restrict__ dwc_b) {
  const int lin = blockIdx.x;               // 0..2047
  const int g2 = (lin & 7) * 256 + (lin >> 3);
  const int bh = g2 >> 4;                   // 0..127
  const int ig = g2 & 15;                   // 4-row group
  const int i0 = ig * 4;
  const int b = bh >> 3, h = bh & 7;
  const int tid = threadIdx.x;
  const int j = tid >> 2;                   // image col (0..63)
  const int g = tid & 3;                    // channel group
  const int d0 = g * 8;
  const int wave = tid >> 6, lane = tid & 63;

  __shared__ float w_s[800];                // [tap][ch]
  __shared__ float b_s[32];
  __shared__ unsigned short v_s[8 * 64 * 32];  // [halo-row][col][ch] 32 KB

  // stage v rows i0-2 .. i0+5 (8 rows; OOB rows skipped, masked at use)
#pragma unroll
  for (int rr = 0; rr < 8; ++rr) {
    const int ii = i0 + rr - 2;             // block-uniform condition
    if (ii < 0 || ii >= 64) continue;
    gload_lds16(qkv + ((size_t)(b * N_ + ii * 64 + wave * 16 + (lane >> 2))) * QKVC +
                    2 * C_ + h * HD_ + (lane & 3) * 8,
                &v_s[rr * 2048 + wave * 512]);
  }
  for (int p = tid; p < 800; p += 256)
    w_s[p] = dwc_w[(p & 31) * 25 + (p >> 5)];
  if (tid < 32) b_s[tid] = dwc_b[tid];
  __syncthreads();   // drains vmcnt -> staged v visible

#pragma unroll
  for (int r = 0; r < 4; ++r) {
    const int i = i0 + r;
    float fm[8];
#pragma unroll
    for (int dd = 0; dd < 8; ++dd) fm[dd] = b_s[d0 + dd];
#pragma unroll
    for (int kr = 0; kr < 5; ++kr) {
      const int ii = i + kr - 2;
      if (ii < 0 || ii >= 64) continue;
      const int lr = r + kr;                // LDS halo row
#pragma unroll
      for (int kj = 0; kj < 5; ++kj) {
        const int jj = j + kj - 2;
        if (jj < 0 || jj >= 64) continue;
        const unsigned int* vr = reinterpret_cast<const unsigned int*>(
            &v_s[lr * 2048 + jj * 32 + d0]);
        const float* wt = &w_s[(kr * 5 + kj) * 32 + d0];
#pragma unroll
        for (int p = 0; p < 4; ++p) {
          const unsigned int vu = vr[p];
          fm[2 * p + 0] += blo(vu) * wt[2 * p + 0];
          fm[2 * p + 1] += bhi(vu) * wt[2 * p + 1];
        }
      }
    }
    // RMW: add conv into attn output (q-slot)
    unsigned int* orow = reinterpret_cast<unsigned int*>(
        qkv + ((size_t)(b * N_ + i * 64 + j)) * QKVC + h * HD_ + d0);
    uint4 cur = *reinterpret_cast<const uint4*>(orow);
    unsigned int o[4] = {cur.x, cur.y, cur.z, cur.w};
#pragma unroll
    for (int p = 0; p < 4; ++p) {
      const unsigned int lo = f2b(blo(o[p]) + fm[2 * p + 0]);
      const unsigned int hi = f2b(bhi(o[p]) + fm[2 * p + 1]);
      o[p] = lo | (hi << 16);
    }
    *reinterpret_cast<uint4*>(orow) = make_uint4(o[0], o[1], o[2], o[3]);
  }
}

// ---------------------------------------------------------------------------
extern "C" void kernel_launch(void* const* d_in, const int* in_sizes, int n_in,
                              void* d_out, int out_size, void* d_ws,
                              size_t ws_size, hipStream_t stream) {
  (void)in_sizes; (void)n_in; (void)out_size; (void)ws_size;
  const float* x      = (const float*)d_in[0];
  const float* qkv_w  = (const float*)d_in[1];
  const float* qkv_b  = (const float*)d_in[2];
  const float* proj_w = (const float*)d_in[3];
  const float* proj_b = (const float*)d_in[4];
  const float* dwc_w  = (const float*)d_in[5];
  const float* dwc_b  = (const float*)d_in[6];
  const float* scale  = (const float*)d_in[7];
  float* out = (float*)d_out;

  char* w = (char*)d_ws;
  unsigned short* xT   = (unsigned short*)w; w += (size_t)M_ * C_ * 2;     // 33.6MB
  unsigned short* qkvb = (unsigned short*)w; w += (size_t)M_ * QKVC * 2;   // 100.7MB
  // Reserve space for BOTH weight matrices (round-3 NaN was wp aliasing kvp).
  unsigned short* wq   = (unsigned short*)w; w += (size_t)(QKVC + C_) * C_ * 2;
  unsigned short* wp   = wq + (size_t)QKVC * C_;
  float* kvp   = (float*)w;                  w += (size_t)KVP_CHUNKS * 128 * 1024 * 4;
  float* ksp   = (float*)w;                  w += (size_t)KVP_CHUNKS * 128 * 32 * 4;
  float* rscb  = (float*)w;                  w += 256 * 4;

  k_prep_scale<<<1, 256, 0, stream>>>(scale, rscb);
  k_cast_x<<<dim3(N_ / 32, C_ / 32, B_), 256, 0, stream>>>(x, xT);
  k_cast_w<<<256, 256, 0, stream>>>(qkv_w, proj_w, wq);
  k_gemm<256, 0, 6><<<dim3(512, 6), 256, 0, stream>>>(
      xT, wq, qkv_b, (void*)qkvb);
  k_focus<<<M_ / 4, 256, 0, stream>>>(qkvb, rscb);
  k_kv_part<<<dim3(128, KVP_CHUNKS), 256, 0, stream>>>(qkvb, kvp, ksp);
  k_attn_mfma<<<dim3(N_ / 256, 128), 256, 0, stream>>>(qkvb, kvp, ksp);
  k_conv<<<2048, 256, 0, stream>>>(qkvb, dwc_w, dwc_b);
  k_gemm<768, 1, 2><<<dim3(512, 2), 256, 0, stream>>>(
      qkvb, wp, proj_b, (void*)out);
}

// Round 18
// 202.782 us; speedup vs baseline: 1.0728x; 1.0391x over previous
//
#include <hip/hip_runtime.h>
#include <cmath>

#define B_   16
#define C_   256
#define HW_  64
#define N_   4096          // 64*64
#define NH_  8
#define HD_  32
#define M_   (B_ * N_)     // 65536
#define QKVC (3 * C_)      // 768
#define EPS_ 1e-6f

typedef short bf16x8 __attribute__((ext_vector_type(8)));
typedef float f32x4 __attribute__((ext_vector_type(4)));
typedef unsigned int u32x4 __attribute__((ext_vector_type(4)));

__device__ __forceinline__ float b2f(unsigned short u) {
  union { unsigned int i; float f; } v;
  v.i = ((unsigned int)u) << 16;
  return v.f;
}
// bf16 pair extraction from a packed uint (pure register ops)
__device__ __forceinline__ float blo(unsigned int u) {
  union { unsigned int i; float f; } v; v.i = u << 16; return v.f;
}
__device__ __forceinline__ float bhi(unsigned int u) {
  union { unsigned int i; float f; } v; v.i = u & 0xffff0000u; return v.f;
}
__device__ __forceinline__ unsigned short f2b(float f) {
  union { float f; unsigned int i; } v;
  v.f = f;
  unsigned int r = v.i + 0x7FFFu + ((v.i >> 16) & 1u);  // RNE
  return (unsigned short)(r >> 16);
}
__device__ __forceinline__ void gload_lds16(const void* g, void* l) {
  __builtin_amdgcn_global_load_lds(
      (const __attribute__((address_space(1))) void*)g,
      (__attribute__((address_space(3))) void*)l, 16, 0, 0);
}

// ---------------------------------------------------------------------------
// K0a: transpose-cast x [b][c][n] f32 -> xT [b][n][c] bf16
// ---------------------------------------------------------------------------
__global__ __launch_bounds__(256) void k_cast_x(const float* __restrict__ x,
                                                unsigned short* __restrict__ xT) {
  __shared__ float t[32][33];
  const int n0 = blockIdx.x * 32, c0 = blockIdx.y * 32, b = blockIdx.z;
  const int tid = threadIdx.x;
  const int r = tid >> 3, g = (tid & 7) * 4;
  float4 v = *reinterpret_cast<const float4*>(
      &x[((size_t)(b * C_ + c0 + r)) * N_ + n0 + g]);
  t[r][g + 0] = v.x; t[r][g + 1] = v.y; t[r][g + 2] = v.z; t[r][g + 3] = v.w;
  __syncthreads();
  ushort4 o;
  o.x = f2b(t[g + 0][r]); o.y = f2b(t[g + 1][r]);
  o.z = f2b(t[g + 2][r]); o.w = f2b(t[g + 3][r]);
  *reinterpret_cast<ushort4*>(&xT[((size_t)(b * N_ + n0 + r)) * C_ + c0 + g]) = o;
}

// ---------------------------------------------------------------------------
// K0b: cast qkv_w (768x256) and proj_w (256x256) to bf16 (contiguous dst)
// ---------------------------------------------------------------------------
__global__ __launch_bounds__(256) void k_cast_w(const float* __restrict__ w1,
                                                const float* __restrict__ w2,
                                                unsigned short* __restrict__ dst) {
  const int g4 = (blockIdx.x * 256 + threadIdx.x) * 4;  // < 262144
  float4 v;
  if (g4 < 196608) v = *reinterpret_cast<const float4*>(w1 + g4);
  else             v = *reinterpret_cast<const float4*>(w2 + (g4 - 196608));
  ushort4 o;
  o.x = f2b(v.x); o.y = f2b(v.y); o.z = f2b(v.z); o.w = f2b(v.w);
  *reinterpret_cast<ushort4*>(dst + g4) = o;
}

// ---------------------------------------------------------------------------
// K0c: rsc[c] = 1/softplus(scale[c]) — computed ONCE.
// ---------------------------------------------------------------------------
__global__ void k_prep_scale(const float* __restrict__ scale,
                             float* __restrict__ rsc) {
  const int c = threadIdx.x;
  rsc[c] = 1.f / log1pf(expf(scale[c]));
}

// ---------------------------------------------------------------------------
// K1/K6: bf16 MFMA GEMM, 128x128 tile, BK=64, 4 waves (2x2 of 64x64).
// Row-major in-band XCD ordering (round 14). ROUND-18: OUTMODE 1 stores
// flipped nt -> CACHED (A/B test: proj at 41.6 us was neither MFMA- nor
// HBM-bound; nt f32 writes suspected of throttling. proj is the last kernel
// so L2 pollution is harmless).
// ---------------------------------------------------------------------------
template <int LDA, int OUTMODE, int NCOL>
__global__ __launch_bounds__(256) void k_gemm(
    const unsigned short* __restrict__ A, const unsigned short* __restrict__ W,
    const float* __restrict__ bias, void* __restrict__ outp) {
  __shared__ unsigned short As[128 * 64];
  __shared__ unsigned short Bs[128 * 64];
  const int tid = threadIdx.x;
  const int wid = tid >> 6, lane = tid & 63;
  const int lin = blockIdx.x + blockIdx.y * 512;
  const int bandp = lin >> 3;
  const int rowb = bandp / NCOL;
  const int colb = bandp - rowb * NCOL;
  const int m0 = (((lin & 7) << 6) + rowb) * 128;
  const int col0 = colb * 128;
  const int wr = wid >> 1, wc = wid & 1;

  const int lrow = lane >> 3;
  const int sl = (lane & 7) ^ (lrow & 7);  // logical 16B-slot this lane fetches

  f32x4 acc[4][4];
#pragma unroll
  for (int i = 0; i < 4; ++i)
#pragma unroll
    for (int j = 0; j < 4; ++j) acc[i][j] = (f32x4){0.f, 0.f, 0.f, 0.f};

  for (int kt = 0; kt < 4; ++kt) {
    const int k0 = kt * 64;
#pragma unroll
    for (int q = 0; q < 4; ++q) {
      const int chunk = wid * 4 + q;          // 0..15, 8 rows each
      const int row = chunk * 8 + lrow;       // 0..127
      gload_lds16(A + (size_t)(m0 + row) * LDA + k0 + sl * 8, &As[chunk * 512]);
      gload_lds16(W + (size_t)(col0 + row) * 256 + k0 + sl * 8, &Bs[chunk * 512]);
    }
    __syncthreads();  // drains vmcnt -> staged tiles visible

    bf16x8 fa[2][4], fb[2][4];
#pragma unroll
    for (int i = 0; i < 4; ++i) {
      const int ra = wr * 64 + i * 16 + (lane & 15);
      const int rb = wc * 64 + i * 16 + (lane & 15);
#pragma unroll
      for (int ks = 0; ks < 2; ++ks) {
        const int s = ks * 4 + (lane >> 4);
        fa[ks][i] = *reinterpret_cast<const bf16x8*>(
            &As[ra * 64 + ((s ^ (ra & 7)) * 8)]);
        fb[ks][i] = *reinterpret_cast<const bf16x8*>(
            &Bs[rb * 64 + ((s ^ (rb & 7)) * 8)]);
      }
    }
#pragma unroll
    for (int i = 0; i < 4; ++i)
#pragma unroll
      for (int j = 0; j < 4; ++j) {
        acc[i][j] = __builtin_amdgcn_mfma_f32_16x16x32_bf16(fa[0][i], fb[0][j],
                                                            acc[i][j], 0, 0, 0);
        acc[i][j] = __builtin_amdgcn_mfma_f32_16x16x32_bf16(fa[1][i], fb[1][j],
                                                            acc[i][j], 0, 0, 0);
      }
    __syncthreads();
  }

  // C/D layout: col = lane&15, row = (lane>>4)*4 + reg   [m89/m91]
  if (OUTMODE == 0) {
    unsigned short* O = (unsigned short*)outp;
#pragma unroll
    for (int j = 0; j < 4; ++j) {
      const int colg = col0 + wc * 64 + j * 16 + (lane & 15);
      const float bb = bias[colg];
#pragma unroll
      for (int i = 0; i < 4; ++i) {
        const int mrow = m0 + wr * 64 + i * 16 + ((lane >> 4) << 2);
#pragma unroll
        for (int r = 0; r < 4; ++r)
          O[(size_t)(mrow + r) * QKVC + colg] = f2b(acc[i][j][r] + bb);
      }
    }
  } else {
    float* O = (float*)outp;
    const int b = m0 >> 12;
    const int nb0 = (m0 & 4095) + wr * 64;
#pragma unroll
    for (int j = 0; j < 4; ++j) {
      const int colg = col0 + wc * 64 + j * 16 + (lane & 15);
      const float bb = bias[colg];
#pragma unroll
      for (int i = 0; i < 4; ++i) {
        const int nb = nb0 + i * 16 + ((lane >> 4) << 2);
        f32x4 o = acc[i][j];
        o += bb;
        *reinterpret_cast<f32x4*>(&O[((size_t)(b * C_ + colg)) * N_ + nb]) = o;
      }
    }
  }
}

// ---------------------------------------------------------------------------
// K2: focusing feature map, wave-per-token (round 9).
// ---------------------------------------------------------------------------
__global__ __launch_bounds__(256) void k_focus(unsigned short* __restrict__ qkv,
                                               const float* __restrict__ rsc) {
  const int wave = threadIdx.x >> 6, lane = threadIdx.x & 63;
  const int t = blockIdx.x * 4 + wave;        // token
  const size_t base = (size_t)t * QKVC + lane * 4;

  uint2 qu = *reinterpret_cast<const uint2*>(qkv + base);
  uint2 ku = *reinterpret_cast<const uint2*>(qkv + base + C_);
  const f32x4 rs = *reinterpret_cast<const f32x4*>(rsc + lane * 4);

  float q[4], k[4], q3[4], k3[4];
  q[0] = blo(qu.x); q[1] = bhi(qu.x); q[2] = blo(qu.y); q[3] = bhi(qu.y);
  k[0] = blo(ku.x); k[1] = bhi(ku.x); k[2] = blo(ku.y); k[3] = bhi(ku.y);

  float sq2 = 0.f, sq6 = 0.f, sk2 = 0.f, sk6 = 0.f;
#pragma unroll
  for (int i = 0; i < 4; ++i) {
    q[i] = (fmaxf(q[i], 0.f) + EPS_) * rs[i];
    k[i] = (fmaxf(k[i], 0.f) + EPS_) * rs[i];
    const float q2 = q[i] * q[i], k2 = k[i] * k[i];
    q3[i] = q2 * q[i];
    k3[i] = k2 * k[i];
    sq2 += q2; sk2 += k2;
    sq6 += q3[i] * q3[i];
    sk6 += k3[i] * k3[i];
  }
#pragma unroll
  for (int off = 1; off < 64; off <<= 1) {
    sq2 += __shfl_xor(sq2, off);
    sq6 += __shfl_xor(sq6, off);
    sk2 += __shfl_xor(sk2, off);
    sk6 += __shfl_xor(sk6, off);
  }
  const float fq = sqrtf(sq2 / sq6);
  const float fk = sqrtf(sk2 / sk6);

  uint2 oq, ok;
  oq.x = (unsigned int)f2b(q3[0] * fq) | ((unsigned int)f2b(q3[1] * fq) << 16);
  oq.y = (unsigned int)f2b(q3[2] * fq) | ((unsigned int)f2b(q3[3] * fq) << 16);
  ok.x = (unsigned int)f2b(k3[0] * fk) | ((unsigned int)f2b(k3[1] * fk) << 16);
  ok.y = (unsigned int)f2b(k3[2] * fk) | ((unsigned int)f2b(k3[3] * fk) << 16);
  *reinterpret_cast<uint2*>(qkv + base) = oq;
  *reinterpret_cast<uint2*>(qkv + base + C_) = ok;
}

// ---------------------------------------------------------------------------
// K3: kv partials per (bh, chunk of 256 rows): kvp[c][d], ksump[c]
// (round 17: reg-staged f32 LDS, pad-36, 8 barriers, prefetch-before-compute)
// ---------------------------------------------------------------------------
#define KVP_CHUNKS 16
__global__ __launch_bounds__(256) void k_kv_part(
    const unsigned short* __restrict__ qkv, float* __restrict__ kvp,
    float* __restrict__ ksp) {
  const int bh = blockIdx.x;
  const int chunk = blockIdx.y;
  const int b = bh >> 3, h = bh & 7;
  const int tid = threadIdx.x;
  __shared__ float ksf[64 * 36];   // 9.2 KB, row pitch 36 floats (144 B)
  __shared__ float vsf[64 * 36];

  const int c = tid >> 3;            // 0..31
  const int d0 = (tid & 7) * 4;      // 0,4,..,28
  const int srow = tid >> 2;         // staging row 0..63
  const int sseg = (tid & 3) * 8;    // staging element offset
  const int j0 = chunk * 256;

  float a0 = 0.f, a1 = 0.f, a2 = 0.f, a3 = 0.f, ksum = 0.f;

  uint4 ku, vu;
  {
    const size_t rb = ((size_t)(b * N_ + j0 + srow)) * QKVC + h * HD_ + sseg;
    ku = *reinterpret_cast<const uint4*>(qkv + rb + C_);
    vu = *reinterpret_cast<const uint4*>(qkv + rb + 2 * C_);
  }

  for (int t = 0; t < 4; ++t) {
    {  // convert current regs -> f32 LDS (conversion happens ONCE here)
      f32x4 k0 = {blo(ku.x), bhi(ku.x), blo(ku.y), bhi(ku.y)};
      f32x4 k1 = {blo(ku.z), bhi(ku.z), blo(ku.w), bhi(ku.w)};
      f32x4 v0 = {blo(vu.x), bhi(vu.x), blo(vu.y), bhi(vu.y)};
      f32x4 v1 = {blo(vu.z), bhi(vu.z), blo(vu.w), bhi(vu.w)};
      *reinterpret_cast<f32x4*>(&ksf[srow * 36 + sseg]) = k0;
      *reinterpret_cast<f32x4*>(&ksf[srow * 36 + sseg + 4]) = k1;
      *reinterpret_cast<f32x4*>(&vsf[srow * 36 + sseg]) = v0;
      *reinterpret_cast<f32x4*>(&vsf[srow * 36 + sseg + 4]) = v1;
    }
    __syncthreads();
    if (t < 3) {  // issue next-tile loads; they fly under the compute below
      const size_t rb =
          ((size_t)(b * N_ + j0 + (t + 1) * 64 + srow)) * QKVC + h * HD_ + sseg;
      ku = *reinterpret_cast<const uint4*>(qkv + rb + C_);
      vu = *reinterpret_cast<const uint4*>(qkv + rb + 2 * C_);
    }
#pragma unroll 8
    for (int jj = 0; jj < 64; ++jj) {
      const float kc = ksf[jj * 36 + c];
      const f32x4 vv = *reinterpret_cast<const f32x4*>(&vsf[jj * 36 + d0]);
      a0 += kc * vv[0];
      a1 += kc * vv[1];
      a2 += kc * vv[2];
      a3 += kc * vv[3];
      ksum += kc;  // identical across the 8 threads sharing c; one stores
    }
    __syncthreads();  // LDS free to overwrite next iteration
  }

  float* kvo = kvp + ((size_t)chunk * 128 + bh) * 1024 + c * 32 + d0;
  kvo[0] = a0; kvo[1] = a1; kvo[2] = a2; kvo[3] = a3;
  if ((tid & 7) == 0) ksp[((size_t)chunk * 128 + bh) * 32 + c] = ksum;
}

// ---------------------------------------------------------------------------
// K4 (ROUND-18 FUSION): attention MFMA + depthwise conv in ONE kernel.
// Block = (4-row group ig, bh), 2048 blocks, XCD-chunked decode (r15).
// Order: kv_s reduce-fill -> barrier -> ISSUE v-halo gloads (fly under the
// MFMA phase, T14) -> attn MFMA writes q-slot -> barrier (drains gloads +
// q-writes; block-local L1 coherence) -> conv RMWs q-slot. Saves one launch,
// the cross-kernel RMW round-trip, and hides v staging under attn compute.
// LDS ~40 KB -> 4 blocks/CU.
// ---------------------------------------------------------------------------
__global__ __launch_bounds__(256) void k_attn_conv_f(
    unsigned short* __restrict__ qkv, const float* __restrict__ kvp,
    const float* __restrict__ ksp, const float* __restrict__ dwc_w,
    const float* __restrict__ dwc_b) {
  const int lin = blockIdx.x;               // 0..2047
  const int g2 = (lin & 7) * 256 + (lin >> 3);
  const int bh = g2 >> 4;                   // 0..127
  const int ig = g2 & 15;                   // 4-row group
  const int i0 = ig * 4;
  const int b = bh >> 3, h = bh & 7;
  const int tid = threadIdx.x;
  const int wave = tid >> 6, lane = tid & 63;

  __shared__ float kv_s[1024];
  __shared__ float ksum_s[32];
  __shared__ float w_s[800];                // [tap][ch]
  __shared__ float b_s[32];
  __shared__ unsigned short v_s[8 * 64 * 32];  // [halo-row][col][ch] 32 KB

  // ---- kv/ksum 16-chunk reduce fill + conv weights
  for (int pp = tid; pp < 1024; pp += 256) {
    float s = 0.f;
#pragma unroll
    for (int ch = 0; ch < KVP_CHUNKS; ++ch)
      s += kvp[((size_t)ch * 128 + bh) * 1024 + pp];
    kv_s[pp] = s;
  }
  if (tid < 32) {
    float s = 0.f;
#pragma unroll
    for (int ch = 0; ch < KVP_CHUNKS; ++ch)
      s += ksp[((size_t)ch * 128 + bh) * 32 + tid];
    ksum_s[tid] = s;
  }
  for (int p = tid; p < 800; p += 256)
    w_s[p] = dwc_w[(p & 31) * 25 + (p >> 5)];
  if (tid < 32) b_s[tid] = dwc_b[tid];
  __syncthreads();

  // ---- issue v-halo gloads NOW; they fly under the attn MFMA phase
#pragma unroll
  for (int rr = 0; rr < 8; ++rr) {
    const int ii = i0 + rr - 2;             // block-uniform condition
    if (ii < 0 || ii >= 64) continue;
    gload_lds16(qkv + ((size_t)(b * N_ + ii * 64 + wave * 16 + (lane >> 2))) * QKVC +
                    2 * C_ + h * HD_ + (lane & 3) * 8,
                &v_s[rr * 2048 + wave * 512]);
  }

  // ---- attn phase: wave handles image row i0+wave (64 tokens)
  {
    const int kb = (lane >> 4) * 8;
    const int col = lane & 15;
    bf16x8 bh0, bh1, bl0, bl1;
    float ks0[8];
#pragma unroll
    for (int t = 0; t < 8; ++t) {
      const float v0 = kv_s[(kb + t) * 32 + col];
      const float v1 = kv_s[(kb + t) * 32 + col + 16];
      const unsigned short h0 = f2b(v0), h1 = f2b(v1);
      ((unsigned short*)&bh0)[t] = h0;
      ((unsigned short*)&bh1)[t] = h1;
      ((unsigned short*)&bl0)[t] = f2b(v0 - b2f(h0));
      ((unsigned short*)&bl1)[t] = f2b(v1 - b2f(h1));
      ks0[t] = ksum_s[kb + t];
    }
    const int r0 = (i0 + wave) * 64;
#pragma unroll
    for (int rt = 0; rt < 4; ++rt) {
      const int row = r0 + rt * 16 + (lane & 15);
      const bf16x8 a = *reinterpret_cast<const bf16x8*>(
          qkv + (size_t)(b * N_ + row) * QKVC + h * HD_ + kb);
      float zp = 0.f;
#pragma unroll
      for (int t = 0; t < 8; ++t)
        zp += b2f(((const unsigned short*)&a)[t]) * ks0[t];
      zp += __shfl_xor(zp, 16);
      zp += __shfl_xor(zp, 32);
      const float z = 1.f / (zp + EPS_);

      f32x4 acc0 = {0.f, 0.f, 0.f, 0.f}, acc1 = {0.f, 0.f, 0.f, 0.f};
      acc0 = __builtin_amdgcn_mfma_f32_16x16x32_bf16(a, bl0, acc0, 0, 0, 0);
      acc1 = __builtin_amdgcn_mfma_f32_16x16x32_bf16(a, bl1, acc1, 0, 0, 0);
      acc0 = __builtin_amdgcn_mfma_f32_16x16x32_bf16(a, bh0, acc0, 0, 0, 0);
      acc1 = __builtin_amdgcn_mfma_f32_16x16x32_bf16(a, bh1, acc1, 0, 0, 0);

#pragma unroll
      for (int r = 0; r < 4; ++r) {
        const int rr = (lane >> 4) * 4 + r;
        const float zr = __shfl(z, rr);
        unsigned short* op =
            qkv + (size_t)(b * N_ + r0 + rt * 16 + rr) * QKVC + h * HD_;
        op[col] = f2b(acc0[r] * zr);
        op[col + 16] = f2b(acc1[r] * zr);
      }
    }
  }
  __syncthreads();  // drains v-halo gloads AND attn q-slot writes (block-local)

  // ---- conv phase: thread = (image col j, channel group g)
  {
    const int j = tid >> 2;
    const int d0 = (tid & 3) * 8;
#pragma unroll
    for (int r = 0; r < 4; ++r) {
      const int i = i0 + r;
      float fm[8];
#pragma unroll
      for (int dd = 0; dd < 8; ++dd) fm[dd] = b_s[d0 + dd];
#pragma unroll
      for (int kr = 0; kr < 5; ++kr) {
        const int ii = i + kr - 2;
        if (ii < 0 || ii >= 64) continue;
        const int lr = r + kr;              // LDS halo row
#pragma unroll
        for (int kj = 0; kj < 5; ++kj) {
          const int jj = j + kj - 2;
          if (jj < 0 || jj >= 64) continue;
          const unsigned int* vr = reinterpret_cast<const unsigned int*>(
              &v_s[lr * 2048 + jj * 32 + d0]);
          const float* wt = &w_s[(kr * 5 + kj) * 32 + d0];
#pragma unroll
          for (int p = 0; p < 4; ++p) {
            const unsigned int vu = vr[p];
            fm[2 * p + 0] += blo(vu) * wt[2 * p + 0];
            fm[2 * p + 1] += bhi(vu) * wt[2 * p + 1];
          }
        }
      }
      // RMW: add conv into attn output (q-slot; written by this block, L1-hot)
      unsigned int* orow = reinterpret_cast<unsigned int*>(
          qkv + ((size_t)(b * N_ + i * 64 + j)) * QKVC + h * HD_ + d0);
      uint4 cur = *reinterpret_cast<const uint4*>(orow);
      unsigned int o[4] = {cur.x, cur.y, cur.z, cur.w};
#pragma unroll
      for (int p = 0; p < 4; ++p) {
        const unsigned int lo = f2b(blo(o[p]) + fm[2 * p + 0]);
        const unsigned int hi = f2b(bhi(o[p]) + fm[2 * p + 1]);
        o[p] = lo | (hi << 16);
      }
      *reinterpret_cast<uint4*>(orow) = make_uint4(o[0], o[1], o[2], o[3]);
    }
  }
}

// ---------------------------------------------------------------------------
extern "C" void kernel_launch(void* const* d_in, const int* in_sizes, int n_in,
                              void* d_out, int out_size, void* d_ws,
                              size_t ws_size, hipStream_t stream) {
  (void)in_sizes; (void)n_in; (void)out_size; (void)ws_size;
  const float* x      = (const float*)d_in[0];
  const float* qkv_w  = (const float*)d_in[1];
  const float* qkv_b  = (const float*)d_in[2];
  const float* proj_w = (const float*)d_in[3];
  const float* proj_b = (const float*)d_in[4];
  const float* dwc_w  = (const float*)d_in[5];
  const float* dwc_b  = (const float*)d_in[6];
  const float* scale  = (const float*)d_in[7];
  float* out = (float*)d_out;

  char* w = (char*)d_ws;
  unsigned short* xT   = (unsigned short*)w; w += (size_t)M_ * C_ * 2;     // 33.6MB
  unsigned short* qkvb = (unsigned short*)w; w += (size_t)M_ * QKVC * 2;   // 100.7MB
  // Reserve space for BOTH weight matrices (round-3 NaN was wp aliasing kvp).
  unsigned short* wq   = (unsigned short*)w; w += (size_t)(QKVC + C_) * C_ * 2;
  unsigned short* wp   = wq + (size_t)QKVC * C_;
  float* kvp   = (float*)w;                  w += (size_t)KVP_CHUNKS * 128 * 1024 * 4;
  float* ksp   = (float*)w;                  w += (size_t)KVP_CHUNKS * 128 * 32 * 4;
  float* rscb  = (float*)w;                  w += 256 * 4;

  k_prep_scale<<<1, 256, 0, stream>>>(scale, rscb);
  k_cast_x<<<dim3(N_ / 32, C_ / 32, B_), 256, 0, stream>>>(x, xT);
  k_cast_w<<<256, 256, 0, stream>>>(qkv_w, proj_w, wq);
  k_gemm<256, 0, 6><<<dim3(512, 6), 256, 0, stream>>>(
      xT, wq, qkv_b, (void*)qkvb);
  k_focus<<<M_ / 4, 256, 0, stream>>>(qkvb, rscb);
  k_kv_part<<<dim3(128, KVP_CHUNKS), 256, 0, stream>>>(qkvb, kvp, ksp);
  k_attn_conv_f<<<2048, 256, 0, stream>>>(qkvb, kvp, ksp, dwc_w, dwc_b);
  k_gemm<768, 1, 2><<<dim3(512, 2), 256, 0, stream>>>(
      qkvb, wp, proj_b, (void*)out);
}

// Round 19
// 195.930 us; speedup vs baseline: 1.1103x; 1.0350x over previous
//
#include <hip/hip_runtime.h>
#include <cmath>

#define B_   16
#define C_   256
#define HW_  64
#define N_   4096          // 64*64
#define NH_  8
#define HD_  32
#define M_   (B_ * N_)     // 65536
#define QKVC (3 * C_)      // 768
#define EPS_ 1e-6f

typedef short bf16x8 __attribute__((ext_vector_type(8)));
typedef float f32x4 __attribute__((ext_vector_type(4)));
typedef unsigned int u32x4 __attribute__((ext_vector_type(4)));

__device__ __forceinline__ float b2f(unsigned short u) {
  union { unsigned int i; float f; } v;
  v.i = ((unsigned int)u) << 16;
  return v.f;
}
// bf16 pair extraction from a packed uint (pure register ops)
__device__ __forceinline__ float blo(unsigned int u) {
  union { unsigned int i; float f; } v; v.i = u << 16; return v.f;
}
__device__ __forceinline__ float bhi(unsigned int u) {
  union { unsigned int i; float f; } v; v.i = u & 0xffff0000u; return v.f;
}
__device__ __forceinline__ unsigned short f2b(float f) {
  union { float f; unsigned int i; } v;
  v.f = f;
  unsigned int r = v.i + 0x7FFFu + ((v.i >> 16) & 1u);  // RNE
  return (unsigned short)(r >> 16);
}
__device__ __forceinline__ void gload_lds16(const void* g, void* l) {
  __builtin_amdgcn_global_load_lds(
      (const __attribute__((address_space(1))) void*)g,
      (__attribute__((address_space(3))) void*)l, 16, 0, 0);
}

// ---------------------------------------------------------------------------
// K0a: transpose-cast x [b][c][n] f32 -> xT [b][n][c] bf16
// ---------------------------------------------------------------------------
__global__ __launch_bounds__(256) void k_cast_x(const float* __restrict__ x,
                                                unsigned short* __restrict__ xT) {
  __shared__ float t[32][33];
  const int n0 = blockIdx.x * 32, c0 = blockIdx.y * 32, b = blockIdx.z;
  const int tid = threadIdx.x;
  const int r = tid >> 3, g = (tid & 7) * 4;
  float4 v = *reinterpret_cast<const float4*>(
      &x[((size_t)(b * C_ + c0 + r)) * N_ + n0 + g]);
  t[r][g + 0] = v.x; t[r][g + 1] = v.y; t[r][g + 2] = v.z; t[r][g + 3] = v.w;
  __syncthreads();
  ushort4 o;
  o.x = f2b(t[g + 0][r]); o.y = f2b(t[g + 1][r]);
  o.z = f2b(t[g + 2][r]); o.w = f2b(t[g + 3][r]);
  *reinterpret_cast<ushort4*>(&xT[((size_t)(b * N_ + n0 + r)) * C_ + c0 + g]) = o;
}

// ---------------------------------------------------------------------------
// K0b: cast qkv_w (768x256) and proj_w (256x256) to bf16 (contiguous dst)
// ---------------------------------------------------------------------------
__global__ __launch_bounds__(256) void k_cast_w(const float* __restrict__ w1,
                                                const float* __restrict__ w2,
                                                unsigned short* __restrict__ dst) {
  const int g4 = (blockIdx.x * 256 + threadIdx.x) * 4;  // < 262144
  float4 v;
  if (g4 < 196608) v = *reinterpret_cast<const float4*>(w1 + g4);
  else             v = *reinterpret_cast<const float4*>(w2 + (g4 - 196608));
  ushort4 o;
  o.x = f2b(v.x); o.y = f2b(v.y); o.z = f2b(v.z); o.w = f2b(v.w);
  *reinterpret_cast<ushort4*>(dst + g4) = o;
}

// ---------------------------------------------------------------------------
// K0c: rsc[c] = 1/softplus(scale[c]) — computed ONCE.
// ---------------------------------------------------------------------------
__global__ void k_prep_scale(const float* __restrict__ scale,
                             float* __restrict__ rsc) {
  const int c = threadIdx.x;
  rsc[c] = 1.f / log1pf(expf(scale[c]));
}

// ---------------------------------------------------------------------------
// K1/K6: bf16 MFMA GEMM, 128x128 tile, BK=64, 4 waves (2x2 of 64x64).
// Row-major in-band XCD ordering (r14). Cached stores both modes (r18 A/B:
// nt throttled proj and evicted qkv).
// ---------------------------------------------------------------------------
template <int LDA, int OUTMODE, int NCOL>
__global__ __launch_bounds__(256) void k_gemm(
    const unsigned short* __restrict__ A, const unsigned short* __restrict__ W,
    const float* __restrict__ bias, void* __restrict__ outp) {
  __shared__ unsigned short As[128 * 64];
  __shared__ unsigned short Bs[128 * 64];
  const int tid = threadIdx.x;
  const int wid = tid >> 6, lane = tid & 63;
  const int lin = blockIdx.x + blockIdx.y * 512;
  const int bandp = lin >> 3;
  const int rowb = bandp / NCOL;
  const int colb = bandp - rowb * NCOL;
  const int m0 = (((lin & 7) << 6) + rowb) * 128;
  const int col0 = colb * 128;
  const int wr = wid >> 1, wc = wid & 1;

  const int lrow = lane >> 3;
  const int sl = (lane & 7) ^ (lrow & 7);  // logical 16B-slot this lane fetches

  f32x4 acc[4][4];
#pragma unroll
  for (int i = 0; i < 4; ++i)
#pragma unroll
    for (int j = 0; j < 4; ++j) acc[i][j] = (f32x4){0.f, 0.f, 0.f, 0.f};

  for (int kt = 0; kt < 4; ++kt) {
    const int k0 = kt * 64;
#pragma unroll
    for (int q = 0; q < 4; ++q) {
      const int chunk = wid * 4 + q;          // 0..15, 8 rows each
      const int row = chunk * 8 + lrow;       // 0..127
      gload_lds16(A + (size_t)(m0 + row) * LDA + k0 + sl * 8, &As[chunk * 512]);
      gload_lds16(W + (size_t)(col0 + row) * 256 + k0 + sl * 8, &Bs[chunk * 512]);
    }
    __syncthreads();  // drains vmcnt -> staged tiles visible

    bf16x8 fa[2][4], fb[2][4];
#pragma unroll
    for (int i = 0; i < 4; ++i) {
      const int ra = wr * 64 + i * 16 + (lane & 15);
      const int rb = wc * 64 + i * 16 + (lane & 15);
#pragma unroll
      for (int ks = 0; ks < 2; ++ks) {
        const int s = ks * 4 + (lane >> 4);
        fa[ks][i] = *reinterpret_cast<const bf16x8*>(
            &As[ra * 64 + ((s ^ (ra & 7)) * 8)]);
        fb[ks][i] = *reinterpret_cast<const bf16x8*>(
            &Bs[rb * 64 + ((s ^ (rb & 7)) * 8)]);
      }
    }
#pragma unroll
    for (int i = 0; i < 4; ++i)
#pragma unroll
      for (int j = 0; j < 4; ++j) {
        acc[i][j] = __builtin_amdgcn_mfma_f32_16x16x32_bf16(fa[0][i], fb[0][j],
                                                            acc[i][j], 0, 0, 0);
        acc[i][j] = __builtin_amdgcn_mfma_f32_16x16x32_bf16(fa[1][i], fb[1][j],
                                                            acc[i][j], 0, 0, 0);
      }
    __syncthreads();
  }

  // C/D layout: col = lane&15, row = (lane>>4)*4 + reg   [m89/m91]
  if (OUTMODE == 0) {
    unsigned short* O = (unsigned short*)outp;
#pragma unroll
    for (int j = 0; j < 4; ++j) {
      const int colg = col0 + wc * 64 + j * 16 + (lane & 15);
      const float bb = bias[colg];
#pragma unroll
      for (int i = 0; i < 4; ++i) {
        const int mrow = m0 + wr * 64 + i * 16 + ((lane >> 4) << 2);
#pragma unroll
        for (int r = 0; r < 4; ++r)
          O[(size_t)(mrow + r) * QKVC + colg] = f2b(acc[i][j][r] + bb);
      }
    }
  } else {
    float* O = (float*)outp;
    const int b = m0 >> 12;
    const int nb0 = (m0 & 4095) + wr * 64;
#pragma unroll
    for (int j = 0; j < 4; ++j) {
      const int colg = col0 + wc * 64 + j * 16 + (lane & 15);
      const float bb = bias[colg];
#pragma unroll
      for (int i = 0; i < 4; ++i) {
        const int nb = nb0 + i * 16 + ((lane >> 4) << 2);
        f32x4 o = acc[i][j];
        o += bb;
        *reinterpret_cast<f32x4*>(&O[((size_t)(b * C_ + colg)) * N_ + nb]) = o;
      }
    }
  }
}

// ---------------------------------------------------------------------------
// K2: focusing feature map, wave-per-token (round 9).
// ---------------------------------------------------------------------------
__global__ __launch_bounds__(256) void k_focus(unsigned short* __restrict__ qkv,
                                               const float* __restrict__ rsc) {
  const int wave = threadIdx.x >> 6, lane = threadIdx.x & 63;
  const int t = blockIdx.x * 4 + wave;        // token
  const size_t base = (size_t)t * QKVC + lane * 4;

  uint2 qu = *reinterpret_cast<const uint2*>(qkv + base);
  uint2 ku = *reinterpret_cast<const uint2*>(qkv + base + C_);
  const f32x4 rs = *reinterpret_cast<const f32x4*>(rsc + lane * 4);

  float q[4], k[4], q3[4], k3[4];
  q[0] = blo(qu.x); q[1] = bhi(qu.x); q[2] = blo(qu.y); q[3] = bhi(qu.y);
  k[0] = blo(ku.x); k[1] = bhi(ku.x); k[2] = blo(ku.y); k[3] = bhi(ku.y);

  float sq2 = 0.f, sq6 = 0.f, sk2 = 0.f, sk6 = 0.f;
#pragma unroll
  for (int i = 0; i < 4; ++i) {
    q[i] = (fmaxf(q[i], 0.f) + EPS_) * rs[i];
    k[i] = (fmaxf(k[i], 0.f) + EPS_) * rs[i];
    const float q2 = q[i] * q[i], k2 = k[i] * k[i];
    q3[i] = q2 * q[i];
    k3[i] = k2 * k[i];
    sq2 += q2; sk2 += k2;
    sq6 += q3[i] * q3[i];
    sk6 += k3[i] * k3[i];
  }
#pragma unroll
  for (int off = 1; off < 64; off <<= 1) {
    sq2 += __shfl_xor(sq2, off);
    sq6 += __shfl_xor(sq6, off);
    sk2 += __shfl_xor(sk2, off);
    sk6 += __shfl_xor(sk6, off);
  }
  const float fq = sqrtf(sq2 / sq6);
  const float fk = sqrtf(sk2 / sk6);

  uint2 oq, ok;
  oq.x = (unsigned int)f2b(q3[0] * fq) | ((unsigned int)f2b(q3[1] * fq) << 16);
  oq.y = (unsigned int)f2b(q3[2] * fq) | ((unsigned int)f2b(q3[3] * fq) << 16);
  ok.x = (unsigned int)f2b(k3[0] * fk) | ((unsigned int)f2b(k3[1] * fk) << 16);
  ok.y = (unsigned int)f2b(k3[2] * fk) | ((unsigned int)f2b(k3[3] * fk) << 16);
  *reinterpret_cast<uint2*>(qkv + base) = oq;
  *reinterpret_cast<uint2*>(qkv + base + C_) = ok;
}

// ---------------------------------------------------------------------------
// K3: kv partials per (bh, chunk of 256 rows): kvp[c][d], ksump[c]
// (round 17: reg-staged f32 LDS, pad-36, 8 barriers, prefetch-before-compute)
// ---------------------------------------------------------------------------
#define KVP_CHUNKS 16
__global__ __launch_bounds__(256) void k_kv_part(
    const unsigned short* __restrict__ qkv, float* __restrict__ kvp,
    float* __restrict__ ksp) {
  const int bh = blockIdx.x;
  const int chunk = blockIdx.y;
  const int b = bh >> 3, h = bh & 7;
  const int tid = threadIdx.x;
  __shared__ float ksf[64 * 36];   // 9.2 KB, row pitch 36 floats (144 B)
  __shared__ float vsf[64 * 36];

  const int c = tid >> 3;            // 0..31
  const int d0 = (tid & 7) * 4;      // 0,4,..,28
  const int srow = tid >> 2;         // staging row 0..63
  const int sseg = (tid & 3) * 8;    // staging element offset
  const int j0 = chunk * 256;

  float a0 = 0.f, a1 = 0.f, a2 = 0.f, a3 = 0.f, ksum = 0.f;

  uint4 ku, vu;
  {
    const size_t rb = ((size_t)(b * N_ + j0 + srow)) * QKVC + h * HD_ + sseg;
    ku = *reinterpret_cast<const uint4*>(qkv + rb + C_);
    vu = *reinterpret_cast<const uint4*>(qkv + rb + 2 * C_);
  }

  for (int t = 0; t < 4; ++t) {
    {  // convert current regs -> f32 LDS (conversion happens ONCE here)
      f32x4 k0 = {blo(ku.x), bhi(ku.x), blo(ku.y), bhi(ku.y)};
      f32x4 k1 = {blo(ku.z), bhi(ku.z), blo(ku.w), bhi(ku.w)};
      f32x4 v0 = {blo(vu.x), bhi(vu.x), blo(vu.y), bhi(vu.y)};
      f32x4 v1 = {blo(vu.z), bhi(vu.z), blo(vu.w), bhi(vu.w)};
      *reinterpret_cast<f32x4*>(&ksf[srow * 36 + sseg]) = k0;
      *reinterpret_cast<f32x4*>(&ksf[srow * 36 + sseg + 4]) = k1;
      *reinterpret_cast<f32x4*>(&vsf[srow * 36 + sseg]) = v0;
      *reinterpret_cast<f32x4*>(&vsf[srow * 36 + sseg + 4]) = v1;
    }
    __syncthreads();
    if (t < 3) {  // issue next-tile loads; they fly under the compute below
      const size_t rb =
          ((size_t)(b * N_ + j0 + (t + 1) * 64 + srow)) * QKVC + h * HD_ + sseg;
      ku = *reinterpret_cast<const uint4*>(qkv + rb + C_);
      vu = *reinterpret_cast<const uint4*>(qkv + rb + 2 * C_);
    }
#pragma unroll 8
    for (int jj = 0; jj < 64; ++jj) {
      const float kc = ksf[jj * 36 + c];
      const f32x4 vv = *reinterpret_cast<const f32x4*>(&vsf[jj * 36 + d0]);
      a0 += kc * vv[0];
      a1 += kc * vv[1];
      a2 += kc * vv[2];
      a3 += kc * vv[3];
      ksum += kc;  // identical across the 8 threads sharing c; one stores
    }
    __syncthreads();  // LDS free to overwrite next iteration
  }

  float* kvo = kvp + ((size_t)chunk * 128 + bh) * 1024 + c * 32 + d0;
  kvo[0] = a0; kvo[1] = a1; kvo[2] = a2; kvo[3] = a3;
  if ((tid & 7) == 0) ksp[((size_t)chunk * 128 + bh) * 32 + c] = ksum;
}

// ---------------------------------------------------------------------------
// K3b (ROUND-19): reduce 16 chunks ONCE -> kvb[128][1024], ksumb[128][32].
// Round-18's fused kernel re-reduced per block: 2048 blocks x 64 KB = 134 MB
// of L2 reads. This kernel reads 8.4 MB once; fused kernel then reads 4.2 KB.
// ---------------------------------------------------------------------------
__global__ __launch_bounds__(256) void k_kv_reduce(
    const float* __restrict__ kvp, const float* __restrict__ ksp,
    float* __restrict__ kv, float* __restrict__ ksum) {
  const int bh = blockIdx.x;
  for (int p = threadIdx.x; p < 1024; p += 256) {
    float s = 0.f;
#pragma unroll
    for (int ch = 0; ch < KVP_CHUNKS; ++ch)
      s += kvp[((size_t)ch * 128 + bh) * 1024 + p];
    kv[bh * 1024 + p] = s;
  }
  if (threadIdx.x < 32) {
    float s = 0.f;
#pragma unroll
    for (int ch = 0; ch < KVP_CHUNKS; ++ch)
      s += ksp[((size_t)ch * 128 + bh) * 32 + threadIdx.x];
    ksum[bh * 32 + threadIdx.x] = s;
  }
}

// ---------------------------------------------------------------------------
// K4: fused attention MFMA + depthwise conv (r18), ROUND-19 conv restructure:
// halo-row register reuse. Loop over the 8 LDS halo rows x 5 column taps =
// 40 LDS loads/thread (was 100) with ONE unpack each (320 VALU, was 800);
// each loaded value feeds all <=4 affected output rows in fm[4][8] regs.
// LDS traffic 3.3 GB -> 1.3 GB; VALU 1600 -> ~1120 per thread.
// ---------------------------------------------------------------------------
__global__ __launch_bounds__(256) void k_attn_conv_f(
    unsigned short* __restrict__ qkv, const float* __restrict__ kv,
    const float* __restrict__ ksum, const float* __restrict__ dwc_w,
    const float* __restrict__ dwc_b) {
  const int lin = blockIdx.x;               // 0..2047
  const int g2 = (lin & 7) * 256 + (lin >> 3);
  const int bh = g2 >> 4;                   // 0..127
  const int ig = g2 & 15;                   // 4-row group
  const int i0 = ig * 4;
  const int b = bh >> 3, h = bh & 7;
  const int tid = threadIdx.x;
  const int wave = tid >> 6, lane = tid & 63;

  __shared__ float kv_s[1024];
  __shared__ float ksum_s[32];
  __shared__ float w_s[800];                // [tap][ch]
  __shared__ float b_s[32];
  __shared__ unsigned short v_s[8 * 64 * 32];  // [halo-row][col][ch] 32 KB

  // ---- fill kv/ksum (pre-reduced) + conv weights
  for (int pp = tid; pp < 1024; pp += 256) kv_s[pp] = kv[bh * 1024 + pp];
  if (tid < 32) ksum_s[tid] = ksum[bh * 32 + tid];
  for (int p = tid; p < 800; p += 256)
    w_s[p] = dwc_w[(p & 31) * 25 + (p >> 5)];
  if (tid < 32) b_s[tid] = dwc_b[tid];
  __syncthreads();

  // ---- issue v-halo gloads NOW; they fly under the attn MFMA phase
#pragma unroll
  for (int rr = 0; rr < 8; ++rr) {
    const int ii = i0 + rr - 2;             // block-uniform condition
    if (ii < 0 || ii >= 64) continue;
    gload_lds16(qkv + ((size_t)(b * N_ + ii * 64 + wave * 16 + (lane >> 2))) * QKVC +
                    2 * C_ + h * HD_ + (lane & 3) * 8,
                &v_s[rr * 2048 + wave * 512]);
  }

  // ---- attn phase: wave handles image row i0+wave (64 tokens)
  {
    const int kb = (lane >> 4) * 8;
    const int col = lane & 15;
    bf16x8 bh0, bh1, bl0, bl1;
    float ks0[8];
#pragma unroll
    for (int t = 0; t < 8; ++t) {
      const float v0 = kv_s[(kb + t) * 32 + col];
      const float v1 = kv_s[(kb + t) * 32 + col + 16];
      const unsigned short h0 = f2b(v0), h1 = f2b(v1);
      ((unsigned short*)&bh0)[t] = h0;
      ((unsigned short*)&bh1)[t] = h1;
      ((unsigned short*)&bl0)[t] = f2b(v0 - b2f(h0));
      ((unsigned short*)&bl1)[t] = f2b(v1 - b2f(h1));
      ks0[t] = ksum_s[kb + t];
    }
    const int r0 = (i0 + wave) * 64;
#pragma unroll
    for (int rt = 0; rt < 4; ++rt) {
      const int row = r0 + rt * 16 + (lane & 15);
      const bf16x8 a = *reinterpret_cast<const bf16x8*>(
          qkv + (size_t)(b * N_ + row) * QKVC + h * HD_ + kb);
      float zp = 0.f;
#pragma unroll
      for (int t = 0; t < 8; ++t)
        zp += b2f(((const unsigned short*)&a)[t]) * ks0[t];
      zp += __shfl_xor(zp, 16);
      zp += __shfl_xor(zp, 32);
      const float z = 1.f / (zp + EPS_);

      f32x4 acc0 = {0.f, 0.f, 0.f, 0.f}, acc1 = {0.f, 0.f, 0.f, 0.f};
      acc0 = __builtin_amdgcn_mfma_f32_16x16x32_bf16(a, bl0, acc0, 0, 0, 0);
      acc1 = __builtin_amdgcn_mfma_f32_16x16x32_bf16(a, bl1, acc1, 0, 0, 0);
      acc0 = __builtin_amdgcn_mfma_f32_16x16x32_bf16(a, bh0, acc0, 0, 0, 0);
      acc1 = __builtin_amdgcn_mfma_f32_16x16x32_bf16(a, bh1, acc1, 0, 0, 0);

#pragma unroll
      for (int r = 0; r < 4; ++r) {
        const int rr = (lane >> 4) * 4 + r;
        const float zr = __shfl(z, rr);
        unsigned short* op =
            qkv + (size_t)(b * N_ + r0 + rt * 16 + rr) * QKVC + h * HD_;
        op[col] = f2b(acc0[r] * zr);
        op[col + 16] = f2b(acc1[r] * zr);
      }
    }
  }
  __syncthreads();  // drains v-halo gloads AND attn q-slot writes (block-local)

  // ---- conv phase: thread = (image col j, channel group); halo-row reuse
  {
    const int j = tid >> 2;
    const int d0 = (tid & 3) * 8;
    float fm[4][8];
#pragma unroll
    for (int r = 0; r < 4; ++r)
#pragma unroll
      for (int dd = 0; dd < 8; ++dd) fm[r][dd] = b_s[d0 + dd];

#pragma unroll
    for (int lr = 0; lr < 8; ++lr) {        // halo row (image row i0+lr-2)
      const int ii = i0 + lr - 2;
      if (ii < 0 || ii >= 64) continue;     // block-uniform
#pragma unroll
      for (int kj = 0; kj < 5; ++kj) {
        const int jj = j + kj - 2;
        if (jj < 0 || jj >= 64) continue;
        const unsigned int* vr = reinterpret_cast<const unsigned int*>(
            &v_s[lr * 2048 + jj * 32 + d0]);
        float vf[8];
#pragma unroll
        for (int p = 0; p < 4; ++p) {       // unpack ONCE per loaded value
          const unsigned int vu = vr[p];
          vf[2 * p + 0] = blo(vu);
          vf[2 * p + 1] = bhi(vu);
        }
#pragma unroll
        for (int r = 0; r < 4; ++r) {       // all output rows this row feeds
          const int kr = lr - r;            // compile-time after unroll
          if (kr < 0 || kr > 4) continue;
          const float* wt = &w_s[(kr * 5 + kj) * 32 + d0];
#pragma unroll
          for (int dd = 0; dd < 8; ++dd) fm[r][dd] += vf[dd] * wt[dd];
        }
      }
    }

#pragma unroll
    for (int r = 0; r < 4; ++r) {
      const int i = i0 + r;
      unsigned int* orow = reinterpret_cast<unsigned int*>(
          qkv + ((size_t)(b * N_ + i * 64 + j)) * QKVC + h * HD_ + d0);
      uint4 cur = *reinterpret_cast<const uint4*>(orow);
      unsigned int o[4] = {cur.x, cur.y, cur.z, cur.w};
#pragma unroll
      for (int p = 0; p < 4; ++p) {
        const unsigned int lo = f2b(blo(o[p]) + fm[r][2 * p + 0]);
        const unsigned int hi = f2b(bhi(o[p]) + fm[r][2 * p + 1]);
        o[p] = lo | (hi << 16);
      }
      *reinterpret_cast<uint4*>(orow) = make_uint4(o[0], o[1], o[2], o[3]);
    }
  }
}

// ---------------------------------------------------------------------------
extern "C" void kernel_launch(void* const* d_in, const int* in_sizes, int n_in,
                              void* d_out, int out_size, void* d_ws,
                              size_t ws_size, hipStream_t stream) {
  (void)in_sizes; (void)n_in; (void)out_size; (void)ws_size;
  const float* x      = (const float*)d_in[0];
  const float* qkv_w  = (const float*)d_in[1];
  const float* qkv_b  = (const float*)d_in[2];
  const float* proj_w = (const float*)d_in[3];
  const float* proj_b = (const float*)d_in[4];
  const float* dwc_w  = (const float*)d_in[5];
  const float* dwc_b  = (const float*)d_in[6];
  const float* scale  = (const float*)d_in[7];
  float* out = (float*)d_out;

  char* w = (char*)d_ws;
  unsigned short* xT   = (unsigned short*)w; w += (size_t)M_ * C_ * 2;     // 33.6MB
  unsigned short* qkvb = (unsigned short*)w; w += (size_t)M_ * QKVC * 2;   // 100.7MB
  // Reserve space for BOTH weight matrices (round-3 NaN was wp aliasing kvp).
  unsigned short* wq   = (unsigned short*)w; w += (size_t)(QKVC + C_) * C_ * 2;
  unsigned short* wp   = wq + (size_t)QKVC * C_;
  float* kvp   = (float*)w;                  w += (size_t)KVP_CHUNKS * 128 * 1024 * 4;
  float* ksp   = (float*)w;                  w += (size_t)KVP_CHUNKS * 128 * 32 * 4;
  float* kvb   = (float*)w;                  w += 128 * 1024 * 4;
  float* ksumb = (float*)w;                  w += 128 * 32 * 4;
  float* rscb  = (float*)w;                  w += 256 * 4;

  k_prep_scale<<<1, 256, 0, stream>>>(scale, rscb);
  k_cast_x<<<dim3(N_ / 32, C_ / 32, B_), 256, 0, stream>>>(x, xT);
  k_cast_w<<<256, 256, 0, stream>>>(qkv_w, proj_w, wq);
  k_gemm<256, 0, 6><<<dim3(512, 6), 256, 0, stream>>>(
      xT, wq, qkv_b, (void*)qkvb);
  k_focus<<<M_ / 4, 256, 0, stream>>>(qkvb, rscb);
  k_kv_part<<<dim3(128, KVP_CHUNKS), 256, 0, stream>>>(qkvb, kvp, ksp);
  k_kv_reduce<<<128, 256, 0, stream>>>(kvp, ksp, kvb, ksumb);
  k_attn_conv_f<<<2048, 256, 0, stream>>>(qkvb, kvb, ksumb, dwc_w, dwc_b);
  k_gemm<768, 1, 2><<<dim3(512, 2), 256, 0, stream>>>(
      qkvb, wp, proj_b, (void*)out);
}